// Round 7
// baseline (1604.117 us; speedup 1.0000x reference)
//
#include <hip/hip_runtime.h>
#include <hip/hip_bf16.h>
#include <math.h>

#define B_  64
#define S_  16
#define T_  48
#define E_  300
#define H_  150
#define G_  300   // 2H
#define NC_ 300
#define NW_ (B_*S_)     // 1024 word-level batch
#define RW_ (T_*NW_)    // 49152 word rows
#define RS_ (S_*B_)     // 1024 sentence rows

__device__ __forceinline__ float sigm(float x){ return 1.0f/(1.0f+__expf(-x)); }

// ---------------------------------------------------------------------------
// transpose: in[R][C] -> out[C][R]
// ---------------------------------------------------------------------------
__global__ __launch_bounds__(256) void transpose_kernel(
    const float* __restrict__ in, float* __restrict__ out, int R, int C){
  int idx = blockIdx.x*256 + threadIdx.x;
  if (idx >= R*C) return;
  int j = idx % R, e = idx / R;
  out[idx] = in[(size_t)j*C + e];   // out[e][j]
}

// ---------------------------------------------------------------------------
// Whh[2][450][150] -> Wblk[2][38][450][4] : Wblk[d][e4][j][k] = Whh[d][j][4e4+k]
// (zero-padded for e >= 150)
// ---------------------------------------------------------------------------
__global__ __launch_bounds__(256) void prep_whh_kernel(
    const float* __restrict__ Whh, float* __restrict__ Wblk){
  int idx = blockIdx.x*256 + threadIdx.x;
  if (idx >= 2*38*450*4) return;
  int k  = idx & 3;
  int j  = (idx >> 2) % 450;
  int e4 = (idx >> 2) / 450 % 38;
  int d  = idx / (38*450*4);
  int e  = e4*4 + k;
  Wblk[idx] = (e < 150) ? Whh[((size_t)d*450 + j)*150 + e] : 0.f;
}

// ---------------------------------------------------------------------------
// gi[t][n][j] = emb[docs[n,t]] @ Wih^T + bih, via K-major Wt[300][900].
// ---------------------------------------------------------------------------
__global__ __launch_bounds__(256,3) void word_gi_v2(
    const int* __restrict__ docs, const float* __restrict__ emb,
    const float* __restrict__ Wt, const float* __restrict__ bih,
    float* __restrict__ gi){
  __shared__ float A[16][304];
  __shared__ float Wc[2][4*900];
  int r0 = blockIdx.x * 16;
  int t  = r0 >> 10;
  int nb = r0 & 1023;
  for (int idx = threadIdx.x; idx < 16*75; idx += 256){
    int row = idx/75, e4 = idx - row*75;
    int tok = docs[(nb+row)*T_ + t];
    *(float4*)&A[row][e4*4] = *(const float4*)&emb[(size_t)tok*E_ + e4*4];
  }
  const float4* Wt4 = (const float4*)Wt;
  {
    float4* Wb0 = (float4*)Wc[0];
    for (int i4 = threadIdx.x; i4 < 900; i4 += 256) Wb0[i4] = Wt4[i4];
  }
  __syncthreads();
  int q = threadIdx.x;
  float acc[16][4] = {};
  float4 pf0, pf1, pf2, pf3;
  for (int c = 0; c < 75; ++c){
    int cur = c & 1;
    if (c < 74){
      const float4* src = Wt4 + (size_t)(c+1)*900;
      pf0 = src[q]; pf1 = src[q+256]; pf2 = src[q+512];
      if (q < 132) pf3 = src[q+768];
    }
    if (q < 225){
      const float4* wrow = (const float4*)Wc[cur];
      float4 w0 = wrow[q], w1 = wrow[225+q], w2 = wrow[450+q], w3 = wrow[675+q];
#pragma unroll
      for (int i = 0; i < 16; ++i){
        float4 av = *(const float4*)&A[i][c*4];
        acc[i][0] += av.x*w0.x + av.y*w1.x + av.z*w2.x + av.w*w3.x;
        acc[i][1] += av.x*w0.y + av.y*w1.y + av.z*w2.y + av.w*w3.y;
        acc[i][2] += av.x*w0.z + av.y*w1.z + av.z*w2.z + av.w*w3.z;
        acc[i][3] += av.x*w0.w + av.y*w1.w + av.z*w2.w + av.w*w3.w;
      }
    }
    if (c < 74){
      float4* Wbn = (float4*)Wc[cur^1];
      Wbn[q] = pf0; Wbn[q+256] = pf1; Wbn[q+512] = pf2;
      if (q < 132) Wbn[q+768] = pf3;
    }
    __syncthreads();
  }
  if (q < 225){
    int j0 = q*4;
    float4 bb = *(const float4*)&bih[j0];
#pragma unroll
    for (int i = 0; i < 16; ++i){
      float4 o4;
      o4.x = acc[i][0]+bb.x; o4.y = acc[i][1]+bb.y;
      o4.z = acc[i][2]+bb.z; o4.w = acc[i][3]+bb.w;
      *(float4*)&gi[((size_t)(t*NW_) + nb + i)*900 + j0] = o4;
    }
  }
}

// sentence-level gi (tiny: 64 blocks)
__global__ __launch_bounds__(256) void sent_gi_kernel(
    const float* __restrict__ sv, const float* __restrict__ Wih,
    const float* __restrict__ bih, float* __restrict__ gi){
  __shared__ float A[16][G_];
  int r0 = blockIdx.x * 16;
  int s  = r0 >> 6;
  int bb_ = r0 & 63;
  for (int idx = threadIdx.x; idx < 16*75; idx += 256){
    int row = idx / 75, e4 = idx - row*75;
    *(float4*)&A[row][e4*4] =
        *(const float4*)&sv[(((size_t)(bb_+row))*S_ + s)*G_ + e4*4];
  }
  __syncthreads();
  int q = threadIdx.x;
  if (q >= 225) return;
  int j0 = q*4;
  const float4* w0 = (const float4*)(Wih + (size_t)(j0  )*G_);
  const float4* w1 = (const float4*)(Wih + (size_t)(j0+1)*G_);
  const float4* w2 = (const float4*)(Wih + (size_t)(j0+2)*G_);
  const float4* w3 = (const float4*)(Wih + (size_t)(j0+3)*G_);
  float acc[16][4];
#pragma unroll
  for (int i=0;i<16;i++){ acc[i][0]=0.f; acc[i][1]=0.f; acc[i][2]=0.f; acc[i][3]=0.f; }
  for (int e4=0; e4<75; e4++){
    float4 b0=w0[e4], b1=w1[e4], b2=w2[e4], b3=w3[e4];
#pragma unroll
    for (int i=0;i<16;i++){
      float4 av = *(const float4*)&A[i][e4*4];
      acc[i][0] += av.x*b0.x + av.y*b0.y + av.z*b0.z + av.w*b0.w;
      acc[i][1] += av.x*b1.x + av.y*b1.y + av.z*b1.z + av.w*b1.w;
      acc[i][2] += av.x*b2.x + av.y*b2.y + av.z*b2.z + av.w*b2.w;
      acc[i][3] += av.x*b3.x + av.y*b3.y + av.z*b3.z + av.w*b3.w;
    }
  }
  float4 bb = *(const float4*)&bih[j0];
#pragma unroll
  for (int i=0;i<16;i++){
    float4 o4;
    o4.x = acc[i][0]+bb.x; o4.y = acc[i][1]+bb.y;
    o4.z = acc[i][2]+bb.z; o4.w = acc[i][3]+bb.w;
    *(float4*)&gi[((size_t)(s*B_) + bb_ + i)*900 + j0] = o4;
  }
}

// ---------------------------------------------------------------------------
// GRU scan v4 (persistent-RNN style): block = R rows x 1 direction, 512 thr.
// Thread j<450 keeps its ENTIRE Whh row in registers (float4 Wr[38], from the
// zero-padded coalesced Wblk) -> zero W memory traffic in the loop. Per step:
// GEMM = pure FMA + uniform-address LDS broadcasts of h (free); gh -> LDS once;
// elementwise phase on threads h<150 with register h_old and gi prefetched at
// step top. Two barriers/step, h double-buffered.
// ---------------------------------------------------------------------------
template<int R>
__global__ __launch_bounds__(512,2) void gru_scan_v4(
    const float* __restrict__ gi, const float* __restrict__ Wblk,
    const float* __restrict__ bhh, float* __restrict__ hs,
    int T, int N){
  int d  = blockIdx.y;
  int n0 = blockIdx.x * R;
  __shared__ float hl[2][R][152];
  __shared__ float gh[R][452];
  int tid = threadIdx.x;
  for (int idx = tid; idx < 2*R*152; idx += 512) (&hl[0][0][0])[idx] = 0.f;

  bool jact = tid < 450;
  bool hact = tid < 150;
  float4 Wr[38];
  float bj = 0.f;
  {
    const float4* Wb4 = (const float4*)(Wblk + (size_t)d*38*1800);
    int jj = jact ? tid : 0;
#pragma unroll
    for (int e4 = 0; e4 < 38; ++e4) Wr[e4] = Wb4[e4*450 + jj];
    if (jact) bj = bhh[d*450 + tid];
  }
  float hreg[R];
#pragma unroll
  for (int i=0;i<R;i++) hreg[i] = 0.f;
  int buf = 0;
  __syncthreads();

  for (int step = 0; step < T; ++step){
    int t = d ? (T-1-step) : step;
    const float* gib = gi + ((size_t)t*N + n0)*900 + d*450;
    // prefetch gi needed by the elementwise phase (hidden under GEMM)
    float pre[R][3];
    if (hact){
#pragma unroll
      for (int i=0;i<R;i++){
        pre[i][0] = gib[(size_t)i*900 + tid];
        pre[i][1] = gib[(size_t)i*900 + 150 + tid];
        pre[i][2] = gib[(size_t)i*900 + 300 + tid];
      }
    }
    // GEMM: gh[i][j] = Whh[j] . h[i]  (W in regs, h broadcast from LDS)
    if (jact){
      float acc[R];
#pragma unroll
      for (int i=0;i<R;i++) acc[i] = 0.f;
#pragma unroll 2
      for (int e4 = 0; e4 < 38; ++e4){
        float4 w = Wr[e4];
#pragma unroll
        for (int i=0;i<R;i++){
          float4 hv = *(const float4*)&hl[buf][i][e4*4];
          acc[i] += w.x*hv.x + w.y*hv.y + w.z*hv.z + w.w*hv.w;
        }
      }
#pragma unroll
      for (int i=0;i<R;i++) gh[i][tid] = acc[i] + bj;
    }
    __syncthreads();
    // elementwise GRU update
    if (hact){
#pragma unroll
      for (int i=0;i<R;i++){
        float r  = sigm(pre[i][0] + gh[i][tid]);
        float z  = sigm(pre[i][1] + gh[i][150+tid]);
        float nn = tanhf(pre[i][2] + r*gh[i][300+tid]);
        float h2 = (1.f - z)*nn + z*hreg[i];
        hreg[i] = h2;
        hl[buf^1][i][tid] = h2;
        hs[((size_t)t*N + n0 + i)*G_ + d*H_ + tid] = h2;
      }
    }
    buf ^= 1;
    __syncthreads();
  }
}

// ---------------------------------------------------------------------------
// score[r] = ctx . tanh(hs[r] @ W^T + b) via K-major Wt[300][300].
// ---------------------------------------------------------------------------
__global__ __launch_bounds__(256,2) void att_score_v2(
    const float* __restrict__ hs, const float* __restrict__ Wt,
    const float* __restrict__ bias, const float* __restrict__ ctx,
    float* __restrict__ score, int Rtot){
  __shared__ float A[48][304];
  __shared__ float Wc[2][4*300];
  int r0 = blockIdx.x * 48;
  for (int idx = threadIdx.x; idx < 48*75; idx += 256){
    int row = idx/75, e4 = idx - row*75;
    float4 v; v.x=0.f; v.y=0.f; v.z=0.f; v.w=0.f;
    if (r0 + row < Rtot) v = *(const float4*)&hs[(size_t)(r0+row)*G_ + e4*4];
    *(float4*)&A[row][e4*4] = v;
  }
  const float4* Wt4 = (const float4*)Wt;
  {
    float4* Wb0 = (float4*)Wc[0];
    for (int i4 = threadIdx.x; i4 < 300; i4 += 256) Wb0[i4] = Wt4[i4];
  }
  __syncthreads();
  int tid = threadIdx.x;
  int rg = tid/75, q = tid - rg*75;
  float acc[16][4] = {};
  float4 pf0, pf1;
  for (int c = 0; c < 75; ++c){
    int cur = c & 1;
    if (c < 74){
      const float4* src = Wt4 + (size_t)(c+1)*300;
      pf0 = src[tid];
      if (tid < 44) pf1 = src[tid+256];
    }
    if (tid < 225){
      const float4* wrow = (const float4*)Wc[cur];
      float4 w0 = wrow[q], w1 = wrow[75+q], w2 = wrow[150+q], w3 = wrow[225+q];
      const float* Ab = &A[rg*16][0];
#pragma unroll
      for (int i = 0; i < 16; ++i){
        float4 av = *(const float4*)&Ab[(size_t)i*304 + c*4];
        acc[i][0] += av.x*w0.x + av.y*w1.x + av.z*w2.x + av.w*w3.x;
        acc[i][1] += av.x*w0.y + av.y*w1.y + av.z*w2.y + av.w*w3.y;
        acc[i][2] += av.x*w0.z + av.y*w1.z + av.z*w2.z + av.w*w3.z;
        acc[i][3] += av.x*w0.w + av.y*w1.w + av.z*w2.w + av.w*w3.w;
      }
    }
    if (c < 74){
      float4* Wbn = (float4*)Wc[cur^1];
      Wbn[tid] = pf0;
      if (tid < 44) Wbn[tid+256] = pf1;
    }
    __syncthreads();
  }
  float part[16];
  if (tid < 225){
    int h0 = q*4;
    float4 bb = *(const float4*)&bias[h0];
    float4 cx = *(const float4*)&ctx[h0];
#pragma unroll
    for (int i = 0; i < 16; ++i){
      part[i] = cx.x*tanhf(acc[i][0]+bb.x) + cx.y*tanhf(acc[i][1]+bb.y)
              + cx.z*tanhf(acc[i][2]+bb.z) + cx.w*tanhf(acc[i][3]+bb.w);
    }
  }
  __syncthreads();
  float* Af = &A[0][0];
  if (tid < 225){
#pragma unroll
    for (int i = 0; i < 16; ++i) Af[q*48 + rg*16 + i] = part[i];
  }
  __syncthreads();
  if (tid < 48 && r0 + tid < Rtot){
    float s = 0.f;
    for (int q2 = 0; q2 < 75; ++q2) s += Af[q2*48 + tid];
    score[r0 + tid] = s;
  }
}

// softmax over t (per n) + weighted sum
__global__ __launch_bounds__(256) void att_combine_kernel(
    const float* __restrict__ score, const float* __restrict__ hs,
    float* __restrict__ out, int T, int N){
  int n = blockIdx.x;
  __shared__ float wa[64];
  if (threadIdx.x < T) wa[threadIdx.x] = score[threadIdx.x*N + n];
  __syncthreads();
  float m = -1e30f;
  for (int t=0;t<T;t++) m = fmaxf(m, wa[t]);
  float den = 0.f;
  for (int t=0;t<T;t++) den += __expf(wa[t]-m);
  float inv = 1.f/den;
  __syncthreads();
  if (threadIdx.x < T) wa[threadIdx.x] = __expf(wa[threadIdx.x]-m)*inv;
  __syncthreads();
  for (int g = threadIdx.x; g < G_; g += 256){
    float acc = 0.f;
    for (int t=0;t<T;t++) acc += wa[t] * hs[((size_t)t*N+n)*G_ + g];
    out[(size_t)n*G_ + g] = acc;
  }
}

// one wave per (b,k): both cosine sims
__global__ __launch_bounds__(256) void cossim_kernel(
    const int* __restrict__ cand, const int* __restrict__ sens,
    const float* __restrict__ ent, const float* __restrict__ sv,
    const float* __restrict__ odoc, float* __restrict__ sim){
  int w = (blockIdx.x*256 + threadIdx.x) >> 6;
  int lane = threadIdx.x & 63;
  if (w >= B_*NC_) return;
  int b = w / NC_, k = w - b*NC_;
  const float* c  = ent + (size_t)cand[b*NC_ + k]*E_;
  const float* a1 = sv  + ((size_t)b*S_ + sens[b])*G_;
  const float* a2 = odoc + (size_t)b*G_;
  float d1=0.f,d2=0.f,cc=0.f,n1=0.f,n2=0.f;
  for (int e = lane; e < E_; e += 64){
    float cv=c[e], v1=a1[e], v2=a2[e];
    d1+=v1*cv; d2+=v2*cv; cc+=cv*cv; n1+=v1*v1; n2+=v2*v2;
  }
  for (int off=32; off; off>>=1){
    d1+=__shfl_xor(d1,off); d2+=__shfl_xor(d2,off); cc+=__shfl_xor(cc,off);
    n1+=__shfl_xor(n1,off); n2+=__shfl_xor(n2,off);
  }
  if (lane == 0){
    float nc = sqrtf(cc);
    sim[(size_t)b*600 + k]       = d1 / fmaxf(sqrtf(n1)*nc, 1e-8f);
    sim[(size_t)b*600 + 300 + k] = d2 / fmaxf(sqrtf(n2)*nc, 1e-8f);
  }
}

// score = sim @ linW^T + linb; gold gather; argmax (first-max tie rule)
__global__ __launch_bounds__(256) void final_kernel(
    const float* __restrict__ sim, const float* __restrict__ linW,
    const float* __restrict__ linb, const int* __restrict__ idx,
    float* __restrict__ out){
  int b = blockIdx.x;
  __shared__ float ss[600];
  __shared__ float sc[300];
  __shared__ float bv[256];
  __shared__ int   bi[256];
  for (int j = threadIdx.x; j < 600; j += 256) ss[j] = sim[(size_t)b*600 + j];
  __syncthreads();
  float bestv = -1e30f; int besti = 0;
  for (int i = threadIdx.x; i < 300; i += 256){
    const float4* wr = (const float4*)(linW + (size_t)i*600);
    float acc = linb[i];
    for (int j4=0; j4<150; j4++){
      float4 w = wr[j4];
      int j = j4*4;
      acc += w.x*ss[j] + w.y*ss[j+1] + w.z*ss[j+2] + w.w*ss[j+3];
    }
    sc[i] = acc;
    out[64 + (size_t)b*300 + i] = acc;
    if (acc > bestv){ bestv = acc; besti = i; }
  }
  bv[threadIdx.x] = bestv; bi[threadIdx.x] = besti;
  __syncthreads();
  for (int s=128; s; s>>=1){
    if (threadIdx.x < s){
      float ov = bv[threadIdx.x+s]; int oi = bi[threadIdx.x+s];
      if (ov > bv[threadIdx.x] || (ov == bv[threadIdx.x] && oi < bi[threadIdx.x])){
        bv[threadIdx.x] = ov; bi[threadIdx.x] = oi;
      }
    }
    __syncthreads();
  }
  if (threadIdx.x == 0){
    out[b] = sc[idx[b]-1];
    out[64 + 64*300 + b] = (float)bi[0];
  }
}

extern "C" void kernel_launch(void* const* d_in, const int* in_sizes, int n_in,
                              void* d_out, int out_size, void* d_ws, size_t ws_size,
                              hipStream_t stream){
  const int*   docs  = (const int*)d_in[0];
  const int*   sens  = (const int*)d_in[1];
  const int*   cand  = (const int*)d_in[2];
  const int*   idx   = (const int*)d_in[3];
  const float* wemb  = (const float*)d_in[4];
  const float* eemb  = (const float*)d_in[5];
  const float* Wih_w = (const float*)d_in[6];
  const float* Whh_w = (const float*)d_in[7];
  const float* bih_w = (const float*)d_in[8];
  const float* bhh_w = (const float*)d_in[9];
  const float* attW_w= (const float*)d_in[10];
  const float* attb_w= (const float*)d_in[11];
  const float* ctx_w = (const float*)d_in[12];
  const float* Wih_s = (const float*)d_in[13];
  const float* Whh_s = (const float*)d_in[14];
  const float* bih_s = (const float*)d_in[15];
  const float* bhh_s = (const float*)d_in[16];
  const float* attW_s= (const float*)d_in[17];
  const float* attb_s= (const float*)d_in[18];
  const float* ctx_s = (const float*)d_in[19];
  const float* linW  = (const float*)d_in[20];
  const float* linb  = (const float*)d_in[21];

  float* ws = (float*)d_ws;
  size_t off = 0;
  float* gi_w    = ws + off; off += (size_t)T_*NW_*900;   // 176.9 MB
  float* hs_w    = ws + off; off += (size_t)T_*NW_*G_;    // 59 MB
  float* score_w = ws + off; off += (size_t)T_*NW_;
  float* sv      = ws + off; off += (size_t)NW_*G_;
  float* gi_s    = ws + off; off += (size_t)S_*B_*900;
  float* hs_s    = ws + off; off += (size_t)S_*B_*G_;
  float* score_s = ws + off; off += (size_t)S_*B_;
  float* odoc    = ws + off; off += (size_t)B_*G_;
  float* sim     = ws + off; off += (size_t)B_*600;
  float* Wt_w    = ws + off; off += (size_t)900*300;      // [300][900]
  float* WtA_w   = ws + off; off += (size_t)300*300;
  float* WtA_s   = ws + off; off += (size_t)300*300;
  float* Wblk_w  = ws + off; off += (size_t)2*38*450*4;   // tiled Whh (word)
  float* Wblk_s  = ws + off; off += (size_t)2*38*450*4;   // tiled Whh (sent)

  float* out = (float*)d_out;

  // one-time weight preps
  transpose_kernel<<<(900*300+255)/256, 256, 0, stream>>>(Wih_w, Wt_w, 900, 300);
  transpose_kernel<<<(300*300+255)/256, 256, 0, stream>>>(attW_w, WtA_w, 300, 300);
  transpose_kernel<<<(300*300+255)/256, 256, 0, stream>>>(attW_s, WtA_s, 300, 300);
  prep_whh_kernel<<<(2*38*450*4+255)/256, 256, 0, stream>>>(Whh_w, Wblk_w);
  prep_whh_kernel<<<(2*38*450*4+255)/256, 256, 0, stream>>>(Whh_s, Wblk_s);

  // word level
  word_gi_v2<<<RW_/16, 256, 0, stream>>>(docs, wemb, Wt_w, bih_w, gi_w);
  gru_scan_v4<8><<<dim3(NW_/8, 2), 512, 0, stream>>>(gi_w, Wblk_w, bhh_w,
                                                     hs_w, T_, NW_);
  att_score_v2<<<(RW_+47)/48, 256, 0, stream>>>(hs_w, WtA_w, attb_w,
                                                ctx_w, score_w, RW_);
  att_combine_kernel<<<NW_, 256, 0, stream>>>(score_w, hs_w, sv, T_, NW_);

  // sentence level
  sent_gi_kernel<<<RS_/16, 256, 0, stream>>>(sv, Wih_s, bih_s, gi_s);
  gru_scan_v4<2><<<dim3(B_/2, 2), 512, 0, stream>>>(gi_s, Wblk_s, bhh_s,
                                                    hs_s, S_, B_);
  att_score_v2<<<(RS_+47)/48, 256, 0, stream>>>(hs_s, WtA_s, attb_s,
                                                ctx_s, score_s, RS_);
  att_combine_kernel<<<B_, 256, 0, stream>>>(score_s, hs_s, odoc, S_, B_);

  // similarity + linear + gold + argmax
  cossim_kernel<<<(B_*NC_*64)/256, 256, 0, stream>>>(cand, sens, eemb, sv, odoc, sim);
  final_kernel<<<B_, 256, 0, stream>>>(sim, linW, linb, idx, out);
}

// Round 8
// 1228.646 us; speedup vs baseline: 1.3056x; 1.3056x over previous
//
#include <hip/hip_runtime.h>
#include <hip/hip_bf16.h>
#include <math.h>

#define B_  64
#define S_  16
#define T_  48
#define E_  300
#define H_  150
#define G_  300   // 2H
#define NC_ 300
#define NW_ (B_*S_)     // 1024 word-level batch
#define RW_ (T_*NW_)    // 49152 word rows
#define RS_ (S_*B_)     // 1024 sentence rows

__device__ __forceinline__ float sigm(float x){ return 1.0f/(1.0f+__expf(-x)); }

// ---------------------------------------------------------------------------
// transpose: in[R][C] -> out[C][R]
// ---------------------------------------------------------------------------
__global__ __launch_bounds__(256) void transpose_kernel(
    const float* __restrict__ in, float* __restrict__ out, int R, int C){
  int idx = blockIdx.x*256 + threadIdx.x;
  if (idx >= R*C) return;
  int j = idx % R, e = idx / R;
  out[idx] = in[(size_t)j*C + e];   // out[e][j]
}

// ---------------------------------------------------------------------------
// Whh[2][450][150] -> Wblk[2][38][450][4] : Wblk[d][e4][j][k] = Whh[d][j][4e4+k]
// (zero-padded for e >= 150)
// ---------------------------------------------------------------------------
__global__ __launch_bounds__(256) void prep_whh_kernel(
    const float* __restrict__ Whh, float* __restrict__ Wblk){
  int idx = blockIdx.x*256 + threadIdx.x;
  if (idx >= 2*38*450*4) return;
  int k  = idx & 3;
  int j  = (idx >> 2) % 450;
  int e4 = (idx >> 2) / 450 % 38;
  int d  = idx / (38*450*4);
  int e  = e4*4 + k;
  Wblk[idx] = (e < 150) ? Whh[((size_t)d*450 + j)*150 + e] : 0.f;
}

// ---------------------------------------------------------------------------
// gi[t][n][j] = emb[docs[n,t]] @ Wih^T + bih, via K-major Wt[300][900].
// ---------------------------------------------------------------------------
__global__ __launch_bounds__(256,3) void word_gi_v2(
    const int* __restrict__ docs, const float* __restrict__ emb,
    const float* __restrict__ Wt, const float* __restrict__ bih,
    float* __restrict__ gi){
  __shared__ float A[16][304];
  __shared__ float Wc[2][4*900];
  int r0 = blockIdx.x * 16;
  int t  = r0 >> 10;
  int nb = r0 & 1023;
  for (int idx = threadIdx.x; idx < 16*75; idx += 256){
    int row = idx/75, e4 = idx - row*75;
    int tok = docs[(nb+row)*T_ + t];
    *(float4*)&A[row][e4*4] = *(const float4*)&emb[(size_t)tok*E_ + e4*4];
  }
  const float4* Wt4 = (const float4*)Wt;
  {
    float4* Wb0 = (float4*)Wc[0];
    for (int i4 = threadIdx.x; i4 < 900; i4 += 256) Wb0[i4] = Wt4[i4];
  }
  __syncthreads();
  int q = threadIdx.x;
  float acc[16][4] = {};
  float4 pf0, pf1, pf2, pf3;
  for (int c = 0; c < 75; ++c){
    int cur = c & 1;
    if (c < 74){
      const float4* src = Wt4 + (size_t)(c+1)*900;
      pf0 = src[q]; pf1 = src[q+256]; pf2 = src[q+512];
      if (q < 132) pf3 = src[q+768];
    }
    if (q < 225){
      const float4* wrow = (const float4*)Wc[cur];
      float4 w0 = wrow[q], w1 = wrow[225+q], w2 = wrow[450+q], w3 = wrow[675+q];
#pragma unroll
      for (int i = 0; i < 16; ++i){
        float4 av = *(const float4*)&A[i][c*4];
        acc[i][0] += av.x*w0.x + av.y*w1.x + av.z*w2.x + av.w*w3.x;
        acc[i][1] += av.x*w0.y + av.y*w1.y + av.z*w2.y + av.w*w3.y;
        acc[i][2] += av.x*w0.z + av.y*w1.z + av.z*w2.z + av.w*w3.z;
        acc[i][3] += av.x*w0.w + av.y*w1.w + av.z*w2.w + av.w*w3.w;
      }
    }
    if (c < 74){
      float4* Wbn = (float4*)Wc[cur^1];
      Wbn[q] = pf0; Wbn[q+256] = pf1; Wbn[q+512] = pf2;
      if (q < 132) Wbn[q+768] = pf3;
    }
    __syncthreads();
  }
  if (q < 225){
    int j0 = q*4;
    float4 bb = *(const float4*)&bih[j0];
#pragma unroll
    for (int i = 0; i < 16; ++i){
      float4 o4;
      o4.x = acc[i][0]+bb.x; o4.y = acc[i][1]+bb.y;
      o4.z = acc[i][2]+bb.z; o4.w = acc[i][3]+bb.w;
      *(float4*)&gi[((size_t)(t*NW_) + nb + i)*900 + j0] = o4;
    }
  }
}

// sentence-level gi (tiny: 64 blocks)
__global__ __launch_bounds__(256) void sent_gi_kernel(
    const float* __restrict__ sv, const float* __restrict__ Wih,
    const float* __restrict__ bih, float* __restrict__ gi){
  __shared__ float A[16][G_];
  int r0 = blockIdx.x * 16;
  int s  = r0 >> 6;
  int bb_ = r0 & 63;
  for (int idx = threadIdx.x; idx < 16*75; idx += 256){
    int row = idx / 75, e4 = idx - row*75;
    *(float4*)&A[row][e4*4] =
        *(const float4*)&sv[(((size_t)(bb_+row))*S_ + s)*G_ + e4*4];
  }
  __syncthreads();
  int q = threadIdx.x;
  if (q >= 225) return;
  int j0 = q*4;
  const float4* w0 = (const float4*)(Wih + (size_t)(j0  )*G_);
  const float4* w1 = (const float4*)(Wih + (size_t)(j0+1)*G_);
  const float4* w2 = (const float4*)(Wih + (size_t)(j0+2)*G_);
  const float4* w3 = (const float4*)(Wih + (size_t)(j0+3)*G_);
  float acc[16][4];
#pragma unroll
  for (int i=0;i<16;i++){ acc[i][0]=0.f; acc[i][1]=0.f; acc[i][2]=0.f; acc[i][3]=0.f; }
  for (int e4=0; e4<75; e4++){
    float4 b0=w0[e4], b1=w1[e4], b2=w2[e4], b3=w3[e4];
#pragma unroll
    for (int i=0;i<16;i++){
      float4 av = *(const float4*)&A[i][e4*4];
      acc[i][0] += av.x*b0.x + av.y*b0.y + av.z*b0.z + av.w*b0.w;
      acc[i][1] += av.x*b1.x + av.y*b1.y + av.z*b1.z + av.w*b1.w;
      acc[i][2] += av.x*b2.x + av.y*b2.y + av.z*b2.z + av.w*b2.w;
      acc[i][3] += av.x*b3.x + av.y*b3.y + av.z*b3.z + av.w*b3.w;
    }
  }
  float4 bb = *(const float4*)&bih[j0];
#pragma unroll
  for (int i=0;i<16;i++){
    float4 o4;
    o4.x = acc[i][0]+bb.x; o4.y = acc[i][1]+bb.y;
    o4.z = acc[i][2]+bb.z; o4.w = acc[i][3]+bb.w;
    *(float4*)&gi[((size_t)(s*B_) + bb_ + i)*900 + j0] = o4;
  }
}

// ---------------------------------------------------------------------------
// GRU scan v4b (persistent-RNN, W in registers — FULLY UNROLLED so the Wr
// array has only compile-time indices; rule #20: runtime-indexed ext arrays
// go to scratch, which is what murdered v4: FETCH 1.845 GB of spill traffic).
// ---------------------------------------------------------------------------
template<int R>
__global__ __launch_bounds__(512,2) void gru_scan_v4(
    const float* __restrict__ gi, const float* __restrict__ Wblk,
    const float* __restrict__ bhh, float* __restrict__ hs,
    int T, int N){
  int d  = blockIdx.y;
  int n0 = blockIdx.x * R;
  __shared__ float hl[2][R][152];
  __shared__ float gh[R][452];
  int tid = threadIdx.x;
  for (int idx = tid; idx < 2*R*152; idx += 512) (&hl[0][0][0])[idx] = 0.f;

  bool jact = tid < 450;
  bool hact = tid < 150;
  float4 Wr[38];
  float bj = 0.f;
  {
    const float4* Wb4 = (const float4*)(Wblk + (size_t)d*38*1800);
    int jj = jact ? tid : 0;
#pragma unroll
    for (int e4 = 0; e4 < 38; ++e4) Wr[e4] = Wb4[e4*450 + jj];
    if (jact) bj = bhh[d*450 + tid];
  }
  float hreg[R];
#pragma unroll
  for (int i=0;i<R;i++) hreg[i] = 0.f;
  int buf = 0;
  __syncthreads();

  for (int step = 0; step < T; ++step){
    int t = d ? (T-1-step) : step;
    const float* gib = gi + ((size_t)t*N + n0)*900 + d*450;
    // prefetch gi needed by the elementwise phase (hidden under GEMM)
    float pre[R][3];
    if (hact){
#pragma unroll
      for (int i=0;i<R;i++){
        pre[i][0] = gib[(size_t)i*900 + tid];
        pre[i][1] = gib[(size_t)i*900 + 150 + tid];
        pre[i][2] = gib[(size_t)i*900 + 300 + tid];
      }
    }
    // GEMM: gh[i][j] = Whh[j] . h[i]  (W in regs, h broadcast from LDS)
    if (jact){
      float acc[R];
#pragma unroll
      for (int i=0;i<R;i++) acc[i] = 0.f;
#pragma unroll           // FULL unroll: every Wr index compile-time constant
      for (int e4 = 0; e4 < 38; ++e4){
        float4 w = Wr[e4];
#pragma unroll
        for (int i=0;i<R;i++){
          float4 hv = *(const float4*)&hl[buf][i][e4*4];
          acc[i] += w.x*hv.x + w.y*hv.y + w.z*hv.z + w.w*hv.w;
        }
      }
#pragma unroll
      for (int i=0;i<R;i++) gh[i][tid] = acc[i] + bj;
    }
    __syncthreads();
    // elementwise GRU update
    if (hact){
#pragma unroll
      for (int i=0;i<R;i++){
        float r  = sigm(pre[i][0] + gh[i][tid]);
        float z  = sigm(pre[i][1] + gh[i][150+tid]);
        float nn = tanhf(pre[i][2] + r*gh[i][300+tid]);
        float h2 = (1.f - z)*nn + z*hreg[i];
        hreg[i] = h2;
        hl[buf^1][i][tid] = h2;
        hs[((size_t)t*N + n0 + i)*G_ + d*H_ + tid] = h2;
      }
    }
    buf ^= 1;
    __syncthreads();
  }
}

// ---------------------------------------------------------------------------
// score[r] = ctx . tanh(hs[r] @ W^T + b) via K-major Wt[300][300].
// ---------------------------------------------------------------------------
__global__ __launch_bounds__(256,2) void att_score_v2(
    const float* __restrict__ hs, const float* __restrict__ Wt,
    const float* __restrict__ bias, const float* __restrict__ ctx,
    float* __restrict__ score, int Rtot){
  __shared__ float A[48][304];
  __shared__ float Wc[2][4*300];
  int r0 = blockIdx.x * 48;
  for (int idx = threadIdx.x; idx < 48*75; idx += 256){
    int row = idx/75, e4 = idx - row*75;
    float4 v; v.x=0.f; v.y=0.f; v.z=0.f; v.w=0.f;
    if (r0 + row < Rtot) v = *(const float4*)&hs[(size_t)(r0+row)*G_ + e4*4];
    *(float4*)&A[row][e4*4] = v;
  }
  const float4* Wt4 = (const float4*)Wt;
  {
    float4* Wb0 = (float4*)Wc[0];
    for (int i4 = threadIdx.x; i4 < 300; i4 += 256) Wb0[i4] = Wt4[i4];
  }
  __syncthreads();
  int tid = threadIdx.x;
  int rg = tid/75, q = tid - rg*75;
  float acc[16][4] = {};
  float4 pf0, pf1;
  for (int c = 0; c < 75; ++c){
    int cur = c & 1;
    if (c < 74){
      const float4* src = Wt4 + (size_t)(c+1)*300;
      pf0 = src[tid];
      if (tid < 44) pf1 = src[tid+256];
    }
    if (tid < 225){
      const float4* wrow = (const float4*)Wc[cur];
      float4 w0 = wrow[q], w1 = wrow[75+q], w2 = wrow[150+q], w3 = wrow[225+q];
      const float* Ab = &A[rg*16][0];
#pragma unroll
      for (int i = 0; i < 16; ++i){
        float4 av = *(const float4*)&Ab[(size_t)i*304 + c*4];
        acc[i][0] += av.x*w0.x + av.y*w1.x + av.z*w2.x + av.w*w3.x;
        acc[i][1] += av.x*w0.y + av.y*w1.y + av.z*w2.y + av.w*w3.y;
        acc[i][2] += av.x*w0.z + av.y*w1.z + av.z*w2.z + av.w*w3.z;
        acc[i][3] += av.x*w0.w + av.y*w1.w + av.z*w2.w + av.w*w3.w;
      }
    }
    if (c < 74){
      float4* Wbn = (float4*)Wc[cur^1];
      Wbn[tid] = pf0;
      if (tid < 44) Wbn[tid+256] = pf1;
    }
    __syncthreads();
  }
  float part[16];
  if (tid < 225){
    int h0 = q*4;
    float4 bb = *(const float4*)&bias[h0];
    float4 cx = *(const float4*)&ctx[h0];
#pragma unroll
    for (int i = 0; i < 16; ++i){
      part[i] = cx.x*tanhf(acc[i][0]+bb.x) + cx.y*tanhf(acc[i][1]+bb.y)
              + cx.z*tanhf(acc[i][2]+bb.z) + cx.w*tanhf(acc[i][3]+bb.w);
    }
  }
  __syncthreads();
  float* Af = &A[0][0];
  if (tid < 225){
#pragma unroll
    for (int i = 0; i < 16; ++i) Af[q*48 + rg*16 + i] = part[i];
  }
  __syncthreads();
  if (tid < 48 && r0 + tid < Rtot){
    float s = 0.f;
    for (int q2 = 0; q2 < 75; ++q2) s += Af[q2*48 + tid];
    score[r0 + tid] = s;
  }
}

// softmax over t (per n) + weighted sum
__global__ __launch_bounds__(256) void att_combine_kernel(
    const float* __restrict__ score, const float* __restrict__ hs,
    float* __restrict__ out, int T, int N){
  int n = blockIdx.x;
  __shared__ float wa[64];
  if (threadIdx.x < T) wa[threadIdx.x] = score[threadIdx.x*N + n];
  __syncthreads();
  float m = -1e30f;
  for (int t=0;t<T;t++) m = fmaxf(m, wa[t]);
  float den = 0.f;
  for (int t=0;t<T;t++) den += __expf(wa[t]-m);
  float inv = 1.f/den;
  __syncthreads();
  if (threadIdx.x < T) wa[threadIdx.x] = __expf(wa[threadIdx.x]-m)*inv;
  __syncthreads();
  for (int g = threadIdx.x; g < G_; g += 256){
    float acc = 0.f;
    for (int t=0;t<T;t++) acc += wa[t] * hs[((size_t)t*N+n)*G_ + g];
    out[(size_t)n*G_ + g] = acc;
  }
}

// one wave per (b,k): both cosine sims
__global__ __launch_bounds__(256) void cossim_kernel(
    const int* __restrict__ cand, const int* __restrict__ sens,
    const float* __restrict__ ent, const float* __restrict__ sv,
    const float* __restrict__ odoc, float* __restrict__ sim){
  int w = (blockIdx.x*256 + threadIdx.x) >> 6;
  int lane = threadIdx.x & 63;
  if (w >= B_*NC_) return;
  int b = w / NC_, k = w - b*NC_;
  const float* c  = ent + (size_t)cand[b*NC_ + k]*E_;
  const float* a1 = sv  + ((size_t)b*S_ + sens[b])*G_;
  const float* a2 = odoc + (size_t)b*G_;
  float d1=0.f,d2=0.f,cc=0.f,n1=0.f,n2=0.f;
  for (int e = lane; e < E_; e += 64){
    float cv=c[e], v1=a1[e], v2=a2[e];
    d1+=v1*cv; d2+=v2*cv; cc+=cv*cv; n1+=v1*v1; n2+=v2*v2;
  }
  for (int off=32; off; off>>=1){
    d1+=__shfl_xor(d1,off); d2+=__shfl_xor(d2,off); cc+=__shfl_xor(cc,off);
    n1+=__shfl_xor(n1,off); n2+=__shfl_xor(n2,off);
  }
  if (lane == 0){
    float nc = sqrtf(cc);
    sim[(size_t)b*600 + k]       = d1 / fmaxf(sqrtf(n1)*nc, 1e-8f);
    sim[(size_t)b*600 + 300 + k] = d2 / fmaxf(sqrtf(n2)*nc, 1e-8f);
  }
}

// score = sim @ linW^T + linb; gold gather; argmax (first-max tie rule)
__global__ __launch_bounds__(256) void final_kernel(
    const float* __restrict__ sim, const float* __restrict__ linW,
    const float* __restrict__ linb, const int* __restrict__ idx,
    float* __restrict__ out){
  int b = blockIdx.x;
  __shared__ float ss[600];
  __shared__ float sc[300];
  __shared__ float bv[256];
  __shared__ int   bi[256];
  for (int j = threadIdx.x; j < 600; j += 256) ss[j] = sim[(size_t)b*600 + j];
  __syncthreads();
  float bestv = -1e30f; int besti = 0;
  for (int i = threadIdx.x; i < 300; i += 256){
    const float4* wr = (const float4*)(linW + (size_t)i*600);
    float acc = linb[i];
    for (int j4=0; j4<150; j4++){
      float4 w = wr[j4];
      int j = j4*4;
      acc += w.x*ss[j] + w.y*ss[j+1] + w.z*ss[j+2] + w.w*ss[j+3];
    }
    sc[i] = acc;
    out[64 + (size_t)b*300 + i] = acc;
    if (acc > bestv){ bestv = acc; besti = i; }
  }
  bv[threadIdx.x] = bestv; bi[threadIdx.x] = besti;
  __syncthreads();
  for (int s=128; s; s>>=1){
    if (threadIdx.x < s){
      float ov = bv[threadIdx.x+s]; int oi = bi[threadIdx.x+s];
      if (ov > bv[threadIdx.x] || (ov == bv[threadIdx.x] && oi < bi[threadIdx.x])){
        bv[threadIdx.x] = ov; bi[threadIdx.x] = oi;
      }
    }
    __syncthreads();
  }
  if (threadIdx.x == 0){
    out[b] = sc[idx[b]-1];
    out[64 + 64*300 + b] = (float)bi[0];
  }
}

extern "C" void kernel_launch(void* const* d_in, const int* in_sizes, int n_in,
                              void* d_out, int out_size, void* d_ws, size_t ws_size,
                              hipStream_t stream){
  const int*   docs  = (const int*)d_in[0];
  const int*   sens  = (const int*)d_in[1];
  const int*   cand  = (const int*)d_in[2];
  const int*   idx   = (const int*)d_in[3];
  const float* wemb  = (const float*)d_in[4];
  const float* eemb  = (const float*)d_in[5];
  const float* Wih_w = (const float*)d_in[6];
  const float* Whh_w = (const float*)d_in[7];
  const float* bih_w = (const float*)d_in[8];
  const float* bhh_w = (const float*)d_in[9];
  const float* attW_w= (const float*)d_in[10];
  const float* attb_w= (const float*)d_in[11];
  const float* ctx_w = (const float*)d_in[12];
  const float* Wih_s = (const float*)d_in[13];
  const float* Whh_s = (const float*)d_in[14];
  const float* bih_s = (const float*)d_in[15];
  const float* bhh_s = (const float*)d_in[16];
  const float* attW_s= (const float*)d_in[17];
  const float* attb_s= (const float*)d_in[18];
  const float* ctx_s = (const float*)d_in[19];
  const float* linW  = (const float*)d_in[20];
  const float* linb  = (const float*)d_in[21];

  float* ws = (float*)d_ws;
  size_t off = 0;
  float* gi_w    = ws + off; off += (size_t)T_*NW_*900;   // 176.9 MB
  float* hs_w    = ws + off; off += (size_t)T_*NW_*G_;    // 59 MB
  float* score_w = ws + off; off += (size_t)T_*NW_;
  float* sv      = ws + off; off += (size_t)NW_*G_;
  float* gi_s    = ws + off; off += (size_t)S_*B_*900;
  float* hs_s    = ws + off; off += (size_t)S_*B_*G_;
  float* score_s = ws + off; off += (size_t)S_*B_;
  float* odoc    = ws + off; off += (size_t)B_*G_;
  float* sim     = ws + off; off += (size_t)B_*600;
  float* Wt_w    = ws + off; off += (size_t)900*300;      // [300][900]
  float* WtA_w   = ws + off; off += (size_t)300*300;
  float* WtA_s   = ws + off; off += (size_t)300*300;
  float* Wblk_w  = ws + off; off += (size_t)2*38*450*4;   // tiled Whh (word)
  float* Wblk_s  = ws + off; off += (size_t)2*38*450*4;   // tiled Whh (sent)

  float* out = (float*)d_out;

  // one-time weight preps
  transpose_kernel<<<(900*300+255)/256, 256, 0, stream>>>(Wih_w, Wt_w, 900, 300);
  transpose_kernel<<<(300*300+255)/256, 256, 0, stream>>>(attW_w, WtA_w, 300, 300);
  transpose_kernel<<<(300*300+255)/256, 256, 0, stream>>>(attW_s, WtA_s, 300, 300);
  prep_whh_kernel<<<(2*38*450*4+255)/256, 256, 0, stream>>>(Whh_w, Wblk_w);
  prep_whh_kernel<<<(2*38*450*4+255)/256, 256, 0, stream>>>(Whh_s, Wblk_s);

  // word level
  word_gi_v2<<<RW_/16, 256, 0, stream>>>(docs, wemb, Wt_w, bih_w, gi_w);
  gru_scan_v4<8><<<dim3(NW_/8, 2), 512, 0, stream>>>(gi_w, Wblk_w, bhh_w,
                                                     hs_w, T_, NW_);
  att_score_v2<<<(RW_+47)/48, 256, 0, stream>>>(hs_w, WtA_w, attb_w,
                                                ctx_w, score_w, RW_);
  att_combine_kernel<<<NW_, 256, 0, stream>>>(score_w, hs_w, sv, T_, NW_);

  // sentence level
  sent_gi_kernel<<<RS_/16, 256, 0, stream>>>(sv, Wih_s, bih_s, gi_s);
  gru_scan_v4<2><<<dim3(B_/2, 2), 512, 0, stream>>>(gi_s, Wblk_s, bhh_s,
                                                    hs_s, S_, B_);
  att_score_v2<<<(RS_+47)/48, 256, 0, stream>>>(hs_s, WtA_s, attb_s,
                                                ctx_s, score_s, RS_);
  att_combine_kernel<<<B_, 256, 0, stream>>>(score_s, hs_s, odoc, S_, B_);

  // similarity + linear + gold + argmax
  cossim_kernel<<<(B_*NC_*64)/256, 256, 0, stream>>>(cand, sens, eemb, sv, odoc, sim);
  final_kernel<<<B_, 256, 0, stream>>>(sim, linW, linb, idx, out);
}

// Round 9
// 1017.128 us; speedup vs baseline: 1.5771x; 1.2080x over previous
//
#include <hip/hip_runtime.h>
#include <hip/hip_bf16.h>
#include <math.h>

#define B_  64
#define S_  16
#define T_  48
#define E_  300
#define H_  150
#define G_  300   // 2H
#define NC_ 300
#define NW_ (B_*S_)     // 1024 word-level batch
#define RW_ (T_*NW_)    // 49152 word rows
#define RS_ (S_*B_)     // 1024 sentence rows

typedef __attribute__((ext_vector_type(8))) short bf16x8;
typedef __attribute__((ext_vector_type(4))) float f32x4;

__device__ __forceinline__ float sigm(float x){ return 1.0f/(1.0f+__expf(-x)); }

__device__ __forceinline__ ushort f2bf_rne(float x){
  uint u = __float_as_uint(x);
  return (ushort)((u + 0x7FFFu + ((u>>16)&1u)) >> 16);
}

// ---------------------------------------------------------------------------
// transpose: in[R][C] -> out[C][R]
// ---------------------------------------------------------------------------
__global__ __launch_bounds__(256) void transpose_kernel(
    const float* __restrict__ in, float* __restrict__ out, int R, int C){
  int idx = blockIdx.x*256 + threadIdx.x;
  if (idx >= R*C) return;
  int j = idx % R, e = idx / R;
  out[idx] = in[(size_t)j*C + e];   // out[e][j]
}

// ---------------------------------------------------------------------------
// Whh[2][450][150] -> Wblk[2][38][450][4], zero-padded
// ---------------------------------------------------------------------------
__global__ __launch_bounds__(256) void prep_whh_kernel(
    const float* __restrict__ Whh, float* __restrict__ Wblk){
  int idx = blockIdx.x*256 + threadIdx.x;
  if (idx >= 2*38*450*4) return;
  int k  = idx & 3;
  int j  = (idx >> 2) % 450;
  int e4 = (idx >> 2) / 450 % 38;
  int d  = idx / (38*450*4);
  int e  = e4*4 + k;
  Wblk[idx] = (e < 150) ? Whh[((size_t)d*450 + j)*150 + e] : 0.f;
}

// ---------------------------------------------------------------------------
// Wih_w [900][300] fp32 -> Whi/Wlo [912][320] bf16 (hi/lo split, zero-pad)
// ---------------------------------------------------------------------------
__global__ __launch_bounds__(128) void split_w_kernel(
    const float* __restrict__ W, ushort* __restrict__ Whi,
    ushort* __restrict__ Wlo){
  int j = blockIdx.x;   // 0..911
  for (int k = threadIdx.x; k < 320; k += 128){
    float x = (j < 900 && k < 300) ? W[(size_t)j*300 + k] : 0.f;
    ushort hb = f2bf_rne(x);
    float hf = __uint_as_float(((uint)hb)<<16);
    ushort lb = f2bf_rne(x - hf);
    Whi[(size_t)j*320 + k] = hb;
    Wlo[(size_t)j*320 + k] = lb;
  }
}

// ---------------------------------------------------------------------------
// gi = X @ Wih^T + bih via bf16x3 MFMA (error ~2^-15, fp32-faithful).
// Block: 4 waves, M=64 rows (one per wave M-tile of 16), N=912 looped in
// 16-col tiles, K=320 (padded). A: emb gather + hi/lo split -> LDS, a-frags
// persistent in regs. B: double-buffered LDS tiles (global->reg issued before
// MFMA, LDS write after). One barrier per N-tile.
// Fragment pattern: 8 contiguous bf16 per lane at [row][kseg*8] for BOTH
// operands (identical permutation => correct regardless of HW k-slot order).
// C/D: col=lane&15, row=(lane>>4)*4+reg  [HW-verified m89].
// ---------------------------------------------------------------------------
__global__ __launch_bounds__(256) void gi_mfma_kernel(
    const int* __restrict__ docs, const float* __restrict__ emb,
    const ushort* __restrict__ Whi, const ushort* __restrict__ Wlo,
    const float* __restrict__ bih, float* __restrict__ gi){
  __shared__ __align__(16) ushort Ahi[64*328];
  __shared__ __align__(16) ushort Alo[64*328];
  __shared__ __align__(16) ushort Bhi[2][16*328];
  __shared__ __align__(16) ushort Blo[2][16*328];
  __shared__ int toks[64];
  int tid = threadIdx.x;
  int gr0 = blockIdx.x * 64;
  int t  = gr0 >> 10;
  int n0 = gr0 & 1023;
  if (tid < 64) toks[tid] = docs[(n0 + tid)*T_ + t];
  __syncthreads();
  // stage A: gather emb rows, split hi/lo into LDS
  for (int c = tid; c < 64*80; c += 256){
    int row = c / 80, k4 = c - row*80;
    float4 x = make_float4(0.f,0.f,0.f,0.f);
    if (k4 < 75) x = *(const float4*)&emb[(size_t)toks[row]*300 + k4*4];
    ushort h0=f2bf_rne(x.x), h1=f2bf_rne(x.y), h2=f2bf_rne(x.z), h3=f2bf_rne(x.w);
    float l0 = x.x - __uint_as_float(((uint)h0)<<16);
    float l1 = x.y - __uint_as_float(((uint)h1)<<16);
    float l2 = x.z - __uint_as_float(((uint)h2)<<16);
    float l3 = x.w - __uint_as_float(((uint)h3)<<16);
    uint2 ph, pl;
    ph.x = (uint)h0 | ((uint)h1<<16); ph.y = (uint)h2 | ((uint)h3<<16);
    pl.x = (uint)f2bf_rne(l0) | ((uint)f2bf_rne(l1)<<16);
    pl.y = (uint)f2bf_rne(l2) | ((uint)f2bf_rne(l3)<<16);
    *(uint2*)&Ahi[row*328 + k4*4] = ph;
    *(uint2*)&Alo[row*328 + k4*4] = pl;
  }
  // issue B tile 0 global loads (hide under A staging barrier)
  uint4 pb[5];
#pragma unroll
  for (int i=0;i<5;i++){
    int c = tid + i*256;
    int half = c >= 640 ? 1 : 0; int cc = c - half*640;
    int row = cc/40, o16 = cc - row*40;
    const ushort* src = half ? Wlo : Whi;
    pb[i] = *(const uint4*)&src[(size_t)row*320 + o16*8];
  }
  __syncthreads();
  // persistent a-frags
  int w = tid >> 6, L = tid & 63;
  int lrow = L & 15, lseg = L >> 4;
  bf16x8 ah[10], al[10];
  {
    int ab = (w*16 + lrow)*328 + lseg*8;
#pragma unroll
    for (int ks=0; ks<10; ks++){
      ah[ks] = *(const bf16x8*)&Ahi[ab + ks*32];
      al[ks] = *(const bf16x8*)&Alo[ab + ks*32];
    }
  }
  // write B0 into LDS buf0
#pragma unroll
  for (int i=0;i<5;i++){
    int c = tid + i*256;
    int half = c >= 640 ? 1 : 0; int cc = c - half*640;
    int row = cc/40, o16 = cc - row*40;
    ushort* dst = half ? Blo[0] : Bhi[0];
    *(uint4*)&dst[row*328 + o16*8] = pb[i];
  }
  __syncthreads();
  int buf = 0;
  int bfb = lrow*328 + lseg*8;
  for (int nt = 0; nt < 57; ++nt){
    if (nt < 56){
#pragma unroll
      for (int i=0;i<5;i++){
        int c = tid + i*256;
        int half = c >= 640 ? 1 : 0; int cc = c - half*640;
        int row = cc/40, o16 = cc - row*40;
        const ushort* src = half ? Wlo : Whi;
        pb[i] = *(const uint4*)&src[(size_t)((nt+1)*16 + row)*320 + o16*8];
      }
    }
    f32x4 acc = {0.f, 0.f, 0.f, 0.f};
#pragma unroll
    for (int ks=0; ks<10; ks++){
      bf16x8 bh = *(const bf16x8*)&Bhi[buf][bfb + ks*32];
      bf16x8 bl = *(const bf16x8*)&Blo[buf][bfb + ks*32];
      acc = __builtin_amdgcn_mfma_f32_16x16x32_bf16(ah[ks], bh, acc, 0, 0, 0);
      acc = __builtin_amdgcn_mfma_f32_16x16x32_bf16(ah[ks], bl, acc, 0, 0, 0);
      acc = __builtin_amdgcn_mfma_f32_16x16x32_bf16(al[ks], bh, acc, 0, 0, 0);
    }
    int col = nt*16 + lrow;
    if (col < 900){
      float bb = bih[col];
      int rbase = gr0 + w*16 + lseg*4;
#pragma unroll
      for (int r=0;r<4;r++)
        gi[(size_t)(rbase + r)*900 + col] = acc[r] + bb;
    }
    if (nt < 56){
#pragma unroll
      for (int i=0;i<5;i++){
        int c = tid + i*256;
        int half = c >= 640 ? 1 : 0; int cc = c - half*640;
        int row = cc/40, o16 = cc - row*40;
        ushort* dst = half ? Blo[buf^1] : Bhi[buf^1];
        *(uint4*)&dst[row*328 + o16*8] = pb[i];
      }
    }
    __syncthreads();
    buf ^= 1;
  }
}

// sentence-level gi (tiny: 64 blocks)
__global__ __launch_bounds__(256) void sent_gi_kernel(
    const float* __restrict__ sv, const float* __restrict__ Wih,
    const float* __restrict__ bih, float* __restrict__ gi){
  __shared__ float A[16][G_];
  int r0 = blockIdx.x * 16;
  int s  = r0 >> 6;
  int bb_ = r0 & 63;
  for (int idx = threadIdx.x; idx < 16*75; idx += 256){
    int row = idx / 75, e4 = idx - row*75;
    *(float4*)&A[row][e4*4] =
        *(const float4*)&sv[(((size_t)(bb_+row))*S_ + s)*G_ + e4*4];
  }
  __syncthreads();
  int q = threadIdx.x;
  if (q >= 225) return;
  int j0 = q*4;
  const float4* w0 = (const float4*)(Wih + (size_t)(j0  )*G_);
  const float4* w1 = (const float4*)(Wih + (size_t)(j0+1)*G_);
  const float4* w2 = (const float4*)(Wih + (size_t)(j0+2)*G_);
  const float4* w3 = (const float4*)(Wih + (size_t)(j0+3)*G_);
  float acc[16][4];
#pragma unroll
  for (int i=0;i<16;i++){ acc[i][0]=0.f; acc[i][1]=0.f; acc[i][2]=0.f; acc[i][3]=0.f; }
  for (int e4=0; e4<75; e4++){
    float4 b0=w0[e4], b1=w1[e4], b2=w2[e4], b3=w3[e4];
#pragma unroll
    for (int i=0;i<16;i++){
      float4 av = *(const float4*)&A[i][e4*4];
      acc[i][0] += av.x*b0.x + av.y*b0.y + av.z*b0.z + av.w*b0.w;
      acc[i][1] += av.x*b1.x + av.y*b1.y + av.z*b1.z + av.w*b1.w;
      acc[i][2] += av.x*b2.x + av.y*b2.y + av.z*b2.z + av.w*b2.w;
      acc[i][3] += av.x*b3.x + av.y*b3.y + av.z*b3.z + av.w*b3.w;
    }
  }
  float4 bb = *(const float4*)&bih[j0];
#pragma unroll
  for (int i=0;i<16;i++){
    float4 o4;
    o4.x = acc[i][0]+bb.x; o4.y = acc[i][1]+bb.y;
    o4.z = acc[i][2]+bb.z; o4.w = acc[i][3]+bb.w;
    *(float4*)&gi[((size_t)(s*B_) + bb_ + i)*900 + j0] = o4;
  }
}

// ---------------------------------------------------------------------------
// GRU scan v4 (persistent-RNN, W in registers, fully unrolled — rule #20)
// ---------------------------------------------------------------------------
template<int R>
__global__ __launch_bounds__(512,2) void gru_scan_v4(
    const float* __restrict__ gi, const float* __restrict__ Wblk,
    const float* __restrict__ bhh, float* __restrict__ hs,
    int T, int N){
  int d  = blockIdx.y;
  int n0 = blockIdx.x * R;
  __shared__ float hl[2][R][152];
  __shared__ float gh[R][452];
  int tid = threadIdx.x;
  for (int idx = tid; idx < 2*R*152; idx += 512) (&hl[0][0][0])[idx] = 0.f;

  bool jact = tid < 450;
  bool hact = tid < 150;
  float4 Wr[38];
  float bj = 0.f;
  {
    const float4* Wb4 = (const float4*)(Wblk + (size_t)d*38*1800);
    int jj = jact ? tid : 0;
#pragma unroll
    for (int e4 = 0; e4 < 38; ++e4) Wr[e4] = Wb4[e4*450 + jj];
    if (jact) bj = bhh[d*450 + tid];
  }
  float hreg[R];
#pragma unroll
  for (int i=0;i<R;i++) hreg[i] = 0.f;
  int buf = 0;
  __syncthreads();

  for (int step = 0; step < T; ++step){
    int t = d ? (T-1-step) : step;
    const float* gib = gi + ((size_t)t*N + n0)*900 + d*450;
    float pre[R][3];
    if (hact){
#pragma unroll
      for (int i=0;i<R;i++){
        pre[i][0] = gib[(size_t)i*900 + tid];
        pre[i][1] = gib[(size_t)i*900 + 150 + tid];
        pre[i][2] = gib[(size_t)i*900 + 300 + tid];
      }
    }
    if (jact){
      float acc[R];
#pragma unroll
      for (int i=0;i<R;i++) acc[i] = 0.f;
#pragma unroll
      for (int e4 = 0; e4 < 38; ++e4){
        float4 w = Wr[e4];
#pragma unroll
        for (int i=0;i<R;i++){
          float4 hv = *(const float4*)&hl[buf][i][e4*4];
          acc[i] += w.x*hv.x + w.y*hv.y + w.z*hv.z + w.w*hv.w;
        }
      }
#pragma unroll
      for (int i=0;i<R;i++) gh[i][tid] = acc[i] + bj;
    }
    __syncthreads();
    if (hact){
#pragma unroll
      for (int i=0;i<R;i++){
        float r  = sigm(pre[i][0] + gh[i][tid]);
        float z  = sigm(pre[i][1] + gh[i][150+tid]);
        float nn = tanhf(pre[i][2] + r*gh[i][300+tid]);
        float h2 = (1.f - z)*nn + z*hreg[i];
        hreg[i] = h2;
        hl[buf^1][i][tid] = h2;
        hs[((size_t)t*N + n0 + i)*G_ + d*H_ + tid] = h2;
      }
    }
    buf ^= 1;
    __syncthreads();
  }
}

// ---------------------------------------------------------------------------
// score[r] = ctx . tanh(hs[r] @ W^T + b) via K-major Wt[300][300].
// ---------------------------------------------------------------------------
__global__ __launch_bounds__(256,2) void att_score_v2(
    const float* __restrict__ hs, const float* __restrict__ Wt,
    const float* __restrict__ bias, const float* __restrict__ ctx,
    float* __restrict__ score, int Rtot){
  __shared__ float A[48][304];
  __shared__ float Wc[2][4*300];
  int r0 = blockIdx.x * 48;
  for (int idx = threadIdx.x; idx < 48*75; idx += 256){
    int row = idx/75, e4 = idx - row*75;
    float4 v; v.x=0.f; v.y=0.f; v.z=0.f; v.w=0.f;
    if (r0 + row < Rtot) v = *(const float4*)&hs[(size_t)(r0+row)*G_ + e4*4];
    *(float4*)&A[row][e4*4] = v;
  }
  const float4* Wt4 = (const float4*)Wt;
  {
    float4* Wb0 = (float4*)Wc[0];
    for (int i4 = threadIdx.x; i4 < 300; i4 += 256) Wb0[i4] = Wt4[i4];
  }
  __syncthreads();
  int tid = threadIdx.x;
  int rg = tid/75, q = tid - rg*75;
  float acc[16][4] = {};
  float4 pf0, pf1;
  for (int c = 0; c < 75; ++c){
    int cur = c & 1;
    if (c < 74){
      const float4* src = Wt4 + (size_t)(c+1)*300;
      pf0 = src[tid];
      if (tid < 44) pf1 = src[tid+256];
    }
    if (tid < 225){
      const float4* wrow = (const float4*)Wc[cur];
      float4 w0 = wrow[q], w1 = wrow[75+q], w2 = wrow[150+q], w3 = wrow[225+q];
      const float* Ab = &A[rg*16][0];
#pragma unroll
      for (int i = 0; i < 16; ++i){
        float4 av = *(const float4*)&Ab[(size_t)i*304 + c*4];
        acc[i][0] += av.x*w0.x + av.y*w1.x + av.z*w2.x + av.w*w3.x;
        acc[i][1] += av.x*w0.y + av.y*w1.y + av.z*w2.y + av.w*w3.y;
        acc[i][2] += av.x*w0.z + av.y*w1.z + av.z*w2.z + av.w*w3.z;
        acc[i][3] += av.x*w0.w + av.y*w1.w + av.z*w2.w + av.w*w3.w;
      }
    }
    if (c < 74){
      float4* Wbn = (float4*)Wc[cur^1];
      Wbn[tid] = pf0;
      if (tid < 44) Wbn[tid+256] = pf1;
    }
    __syncthreads();
  }
  float part[16];
  if (tid < 225){
    int h0 = q*4;
    float4 bb = *(const float4*)&bias[h0];
    float4 cx = *(const float4*)&ctx[h0];
#pragma unroll
    for (int i = 0; i < 16; ++i){
      part[i] = cx.x*tanhf(acc[i][0]+bb.x) + cx.y*tanhf(acc[i][1]+bb.y)
              + cx.z*tanhf(acc[i][2]+bb.z) + cx.w*tanhf(acc[i][3]+bb.w);
    }
  }
  __syncthreads();
  float* Af = &A[0][0];
  if (tid < 225){
#pragma unroll
    for (int i = 0; i < 16; ++i) Af[q*48 + rg*16 + i] = part[i];
  }
  __syncthreads();
  if (tid < 48 && r0 + tid < Rtot){
    float s = 0.f;
    for (int q2 = 0; q2 < 75; ++q2) s += Af[q2*48 + tid];
    score[r0 + tid] = s;
  }
}

// softmax over t (per n) + weighted sum
__global__ __launch_bounds__(256) void att_combine_kernel(
    const float* __restrict__ score, const float* __restrict__ hs,
    float* __restrict__ out, int T, int N){
  int n = blockIdx.x;
  __shared__ float wa[64];
  if (threadIdx.x < T) wa[threadIdx.x] = score[threadIdx.x*N + n];
  __syncthreads();
  float m = -1e30f;
  for (int t=0;t<T;t++) m = fmaxf(m, wa[t]);
  float den = 0.f;
  for (int t=0;t<T;t++) den += __expf(wa[t]-m);
  float inv = 1.f/den;
  __syncthreads();
  if (threadIdx.x < T) wa[threadIdx.x] = __expf(wa[threadIdx.x]-m)*inv;
  __syncthreads();
  for (int g = threadIdx.x; g < G_; g += 256){
    float acc = 0.f;
    for (int t=0;t<T;t++) acc += wa[t] * hs[((size_t)t*N+n)*G_ + g];
    out[(size_t)n*G_ + g] = acc;
  }
}

// one wave per (b,k): both cosine sims
__global__ __launch_bounds__(256) void cossim_kernel(
    const int* __restrict__ cand, const int* __restrict__ sens,
    const float* __restrict__ ent, const float* __restrict__ sv,
    const float* __restrict__ odoc, float* __restrict__ sim){
  int w = (blockIdx.x*256 + threadIdx.x) >> 6;
  int lane = threadIdx.x & 63;
  if (w >= B_*NC_) return;
  int b = w / NC_, k = w - b*NC_;
  const float* c  = ent + (size_t)cand[b*NC_ + k]*E_;
  const float* a1 = sv  + ((size_t)b*S_ + sens[b])*G_;
  const float* a2 = odoc + (size_t)b*G_;
  float d1=0.f,d2=0.f,cc=0.f,n1=0.f,n2=0.f;
  for (int e = lane; e < E_; e += 64){
    float cv=c[e], v1=a1[e], v2=a2[e];
    d1+=v1*cv; d2+=v2*cv; cc+=cv*cv; n1+=v1*v1; n2+=v2*v2;
  }
  for (int off=32; off; off>>=1){
    d1+=__shfl_xor(d1,off); d2+=__shfl_xor(d2,off); cc+=__shfl_xor(cc,off);
    n1+=__shfl_xor(n1,off); n2+=__shfl_xor(n2,off);
  }
  if (lane == 0){
    float nc = sqrtf(cc);
    sim[(size_t)b*600 + k]       = d1 / fmaxf(sqrtf(n1)*nc, 1e-8f);
    sim[(size_t)b*600 + 300 + k] = d2 / fmaxf(sqrtf(n2)*nc, 1e-8f);
  }
}

// score = sim @ linW^T + linb; gold gather; argmax (first-max tie rule)
__global__ __launch_bounds__(256) void final_kernel(
    const float* __restrict__ sim, const float* __restrict__ linW,
    const float* __restrict__ linb, const int* __restrict__ idx,
    float* __restrict__ out){
  int b = blockIdx.x;
  __shared__ float ss[600];
  __shared__ float sc[300];
  __shared__ float bv[256];
  __shared__ int   bi[256];
  for (int j = threadIdx.x; j < 600; j += 256) ss[j] = sim[(size_t)b*600 + j];
  __syncthreads();
  float bestv = -1e30f; int besti = 0;
  for (int i = threadIdx.x; i < 300; i += 256){
    const float4* wr = (const float4*)(linW + (size_t)i*600);
    float acc = linb[i];
    for (int j4=0; j4<150; j4++){
      float4 w = wr[j4];
      int j = j4*4;
      acc += w.x*ss[j] + w.y*ss[j+1] + w.z*ss[j+2] + w.w*ss[j+3];
    }
    sc[i] = acc;
    out[64 + (size_t)b*300 + i] = acc;
    if (acc > bestv){ bestv = acc; besti = i; }
  }
  bv[threadIdx.x] = bestv; bi[threadIdx.x] = besti;
  __syncthreads();
  for (int s=128; s; s>>=1){
    if (threadIdx.x < s){
      float ov = bv[threadIdx.x+s]; int oi = bi[threadIdx.x+s];
      if (ov > bv[threadIdx.x] || (ov == bv[threadIdx.x] && oi < bi[threadIdx.x])){
        bv[threadIdx.x] = ov; bi[threadIdx.x] = oi;
      }
    }
    __syncthreads();
  }
  if (threadIdx.x == 0){
    out[b] = sc[idx[b]-1];
    out[64 + 64*300 + b] = (float)bi[0];
  }
}

extern "C" void kernel_launch(void* const* d_in, const int* in_sizes, int n_in,
                              void* d_out, int out_size, void* d_ws, size_t ws_size,
                              hipStream_t stream){
  const int*   docs  = (const int*)d_in[0];
  const int*   sens  = (const int*)d_in[1];
  const int*   cand  = (const int*)d_in[2];
  const int*   idx   = (const int*)d_in[3];
  const float* wemb  = (const float*)d_in[4];
  const float* eemb  = (const float*)d_in[5];
  const float* Wih_w = (const float*)d_in[6];
  const float* Whh_w = (const float*)d_in[7];
  const float* bih_w = (const float*)d_in[8];
  const float* bhh_w = (const float*)d_in[9];
  const float* attW_w= (const float*)d_in[10];
  const float* attb_w= (const float*)d_in[11];
  const float* ctx_w = (const float*)d_in[12];
  const float* Wih_s = (const float*)d_in[13];
  const float* Whh_s = (const float*)d_in[14];
  const float* bih_s = (const float*)d_in[15];
  const float* bhh_s = (const float*)d_in[16];
  const float* attW_s= (const float*)d_in[17];
  const float* attb_s= (const float*)d_in[18];
  const float* ctx_s = (const float*)d_in[19];
  const float* linW  = (const float*)d_in[20];
  const float* linb  = (const float*)d_in[21];

  float* ws = (float*)d_ws;
  size_t off = 0;
  float* gi_w    = ws + off; off += (size_t)T_*NW_*900;   // 176.9 MB
  float* hs_w    = ws + off; off += (size_t)T_*NW_*G_;    // 59 MB
  float* score_w = ws + off; off += (size_t)T_*NW_;
  float* sv      = ws + off; off += (size_t)NW_*G_;
  float* gi_s    = ws + off; off += (size_t)S_*B_*900;
  float* hs_s    = ws + off; off += (size_t)S_*B_*G_;
  float* score_s = ws + off; off += (size_t)S_*B_;
  float* odoc    = ws + off; off += (size_t)B_*G_;
  float* sim     = ws + off; off += (size_t)B_*600;
  float* WtA_w   = ws + off; off += (size_t)300*300;
  float* WtA_s   = ws + off; off += (size_t)300*300;
  float* Wblk_w  = ws + off; off += (size_t)2*38*450*4;   // tiled Whh (word)
  float* Wblk_s  = ws + off; off += (size_t)2*38*450*4;   // tiled Whh (sent)
  ushort* Whi    = (ushort*)(ws + off); off += (size_t)912*320/2;  // bf16 hi
  ushort* Wlo    = (ushort*)(ws + off); off += (size_t)912*320/2;  // bf16 lo

  float* out = (float*)d_out;

  // one-time weight preps
  transpose_kernel<<<(300*300+255)/256, 256, 0, stream>>>(attW_w, WtA_w, 300, 300);
  transpose_kernel<<<(300*300+255)/256, 256, 0, stream>>>(attW_s, WtA_s, 300, 300);
  prep_whh_kernel<<<(2*38*450*4+255)/256, 256, 0, stream>>>(Whh_w, Wblk_w);
  prep_whh_kernel<<<(2*38*450*4+255)/256, 256, 0, stream>>>(Whh_s, Wblk_s);
  split_w_kernel<<<912, 128, 0, stream>>>(Wih_w, Whi, Wlo);

  // word level
  gi_mfma_kernel<<<RW_/64, 256, 0, stream>>>(docs, wemb, Whi, Wlo, bih_w, gi_w);
  gru_scan_v4<8><<<dim3(NW_/8, 2), 512, 0, stream>>>(gi_w, Wblk_w, bhh_w,
                                                     hs_w, T_, NW_);
  att_score_v2<<<(RW_+47)/48, 256, 0, stream>>>(hs_w, WtA_w, attb_w,
                                                ctx_w, score_w, RW_);
  att_combine_kernel<<<NW_, 256, 0, stream>>>(score_w, hs_w, sv, T_, NW_);

  // sentence level
  sent_gi_kernel<<<RS_/16, 256, 0, stream>>>(sv, Wih_s, bih_s, gi_s);
  gru_scan_v4<2><<<dim3(B_/2, 2), 512, 0, stream>>>(gi_s, Wblk_s, bhh_s,
                                                    hs_s, S_, B_);
  att_score_v2<<<(RS_+47)/48, 256, 0, stream>>>(hs_s, WtA_s, attb_s,
                                                ctx_s, score_s, RS_);
  att_combine_kernel<<<B_, 256, 0, stream>>>(score_s, hs_s, odoc, S_, B_);

  // similarity + linear + gold + argmax
  cossim_kernel<<<(B_*NC_*64)/256, 256, 0, stream>>>(cand, sens, eemb, sv, odoc, sim);
  final_kernel<<<B_, 256, 0, stream>>>(sim, linW, linb, idx, out);
}

// Round 10
// 951.170 us; speedup vs baseline: 1.6865x; 1.0693x over previous
//
#include <hip/hip_runtime.h>
#include <hip/hip_bf16.h>
#include <math.h>

#define B_  64
#define S_  16
#define T_  48
#define E_  300
#define H_  150
#define G_  300   // 2H
#define NC_ 300
#define NW_ (B_*S_)     // 1024 word-level batch
#define RW_ (T_*NW_)    // 49152 word rows
#define RS_ (S_*B_)     // 1024 sentence rows

typedef __attribute__((ext_vector_type(8))) short bf16x8;
typedef __attribute__((ext_vector_type(4))) float f32x4;

__device__ __forceinline__ float sigm(float x){ return 1.0f/(1.0f+__expf(-x)); }

__device__ __forceinline__ ushort f2bf_rne(float x){
  uint u = __float_as_uint(x);
  return (ushort)((u + 0x7FFFu + ((u>>16)&1u)) >> 16);
}

// ---------------------------------------------------------------------------
// Whh[2][450][150] -> Wblk[2][38][450][4], zero-padded (sentence gru v4)
// ---------------------------------------------------------------------------
__global__ __launch_bounds__(256) void prep_whh_kernel(
    const float* __restrict__ Whh, float* __restrict__ Wblk){
  int idx = blockIdx.x*256 + threadIdx.x;
  if (idx >= 2*38*450*4) return;
  int k  = idx & 3;
  int j  = (idx >> 2) % 450;
  int e4 = (idx >> 2) / 450 % 38;
  int d  = idx / (38*450*4);
  int e  = e4*4 + k;
  Wblk[idx] = (e < 150) ? Whh[((size_t)d*450 + j)*150 + e] : 0.f;
}

// ---------------------------------------------------------------------------
// Whh -> W5[d][kh(3)][e4(13)][j2(225)][c(2)][k(4)]  (word gru v5, zero-pad)
// ---------------------------------------------------------------------------
__global__ __launch_bounds__(256) void prep_whh_v5(
    const float* __restrict__ Whh, float* __restrict__ W5){
  int idx = blockIdx.x*256 + threadIdx.x;
  if (idx >= 2*3*13*225*8) return;
  int kk = idx & 3;
  int r1 = idx >> 2;
  int c  = r1 & 1;
  int r2 = r1 >> 1;
  int j2 = r2 % 225;
  int r3 = r2 / 225;
  int e4 = r3 % 13;
  int r4 = r3 / 13;
  int kh = r4 % 3;
  int d  = r4 / 3;
  int j  = j2*2 + c;
  int kg = (kh*13 + e4)*4 + kk;
  W5[idx] = (kg < 150) ? Whh[((size_t)d*450 + j)*150 + kg] : 0.f;
}

// ---------------------------------------------------------------------------
// generic fp32 -> bf16 hi/lo split: W[R][C] -> Whi/Wlo[gridDim.x][Cp]
// ---------------------------------------------------------------------------
__global__ __launch_bounds__(128) void split_w_gen(
    const float* __restrict__ W, ushort* __restrict__ Whi,
    ushort* __restrict__ Wlo, int R, int C, int Cp){
  int j = blockIdx.x;
  for (int k = threadIdx.x; k < Cp; k += 128){
    float x = (j < R && k < C) ? W[(size_t)j*C + k] : 0.f;
    ushort hb = f2bf_rne(x);
    float hf = __uint_as_float(((uint)hb)<<16);
    Whi[(size_t)j*Cp + k] = hb;
    Wlo[(size_t)j*Cp + k] = f2bf_rne(x - hf);
  }
}

// ---------------------------------------------------------------------------
// gi = X @ Wih^T + bih via bf16x3 MFMA. v2: A-frags loaded per-lane direct
// from emb (in-register hi/lo split) — no A LDS; B double-buffered in 42 KB
// LDS -> 3 blocks/CU (was 1 at 126 KB).
// ---------------------------------------------------------------------------
__global__ __launch_bounds__(256,3) void gi_mfma_v2(
    const int* __restrict__ docs, const float* __restrict__ emb,
    const ushort* __restrict__ Whi, const ushort* __restrict__ Wlo,
    const float* __restrict__ bih, float* __restrict__ gi){
  __shared__ __align__(16) ushort Bhi[2][16*328];
  __shared__ __align__(16) ushort Blo[2][16*328];
  __shared__ int toks[64];
  int tid = threadIdx.x;
  int gr0 = blockIdx.x * 64;
  int t  = gr0 >> 10;
  int n0 = gr0 & 1023;
  if (tid < 64) toks[tid] = docs[(n0 + tid)*T_ + t];
  // issue B tile 0 global loads
  uint4 pb[5];
#pragma unroll
  for (int i=0;i<5;i++){
    int c = tid + i*256;
    int half = (c >= 640) ? 1 : 0; int cc = c - half*640;
    int row = cc/40, o16 = cc - row*40;
    const ushort* src = half ? Wlo : Whi;
    pb[i] = *(const uint4*)&src[(size_t)row*320 + o16*8];
  }
  __syncthreads();   // toks visible
  int w = tid >> 6, L = tid & 63;
  int lrow = L & 15, lseg = L >> 4;
  const float* aptr = emb + (size_t)toks[w*16 + lrow]*300;
  bf16x8 ah[10], al[10];
#pragma unroll
  for (int ks=0; ks<10; ks++){
    int k0 = ks*32 + lseg*8;
    float x[8];
    if (k0 + 8 <= 300){
      float4 v0 = *(const float4*)&aptr[k0];
      float4 v1 = *(const float4*)&aptr[k0+4];
      x[0]=v0.x; x[1]=v0.y; x[2]=v0.z; x[3]=v0.w;
      x[4]=v1.x; x[5]=v1.y; x[6]=v1.z; x[7]=v1.w;
    } else {
#pragma unroll
      for (int u=0;u<8;u++) x[u] = (k0+u < 300) ? aptr[k0+u] : 0.f;
    }
#pragma unroll
    for (int u=0;u<8;u++){
      ushort hb = f2bf_rne(x[u]);
      float lo = x[u] - __uint_as_float(((uint)hb)<<16);
      ah[ks][u] = (short)hb;
      al[ks][u] = (short)f2bf_rne(lo);
    }
  }
  // write B0 into LDS buf0
#pragma unroll
  for (int i=0;i<5;i++){
    int c = tid + i*256;
    int half = (c >= 640) ? 1 : 0; int cc = c - half*640;
    int row = cc/40, o16 = cc - row*40;
    ushort* dst = half ? Blo[0] : Bhi[0];
    *(uint4*)&dst[row*328 + o16*8] = pb[i];
  }
  __syncthreads();
  int buf = 0;
  int bfb = lrow*328 + lseg*8;
  for (int nt = 0; nt < 57; ++nt){
    if (nt < 56){
#pragma unroll
      for (int i=0;i<5;i++){
        int c = tid + i*256;
        int half = (c >= 640) ? 1 : 0; int cc = c - half*640;
        int row = cc/40, o16 = cc - row*40;
        const ushort* src = half ? Wlo : Whi;
        pb[i] = *(const uint4*)&src[(size_t)((nt+1)*16 + row)*320 + o16*8];
      }
    }
    f32x4 acc = {0.f, 0.f, 0.f, 0.f};
#pragma unroll
    for (int ks=0; ks<10; ks++){
      bf16x8 bh = *(const bf16x8*)&Bhi[buf][bfb + ks*32];
      bf16x8 bl = *(const bf16x8*)&Blo[buf][bfb + ks*32];
      acc = __builtin_amdgcn_mfma_f32_16x16x32_bf16(ah[ks], bh, acc, 0, 0, 0);
      acc = __builtin_amdgcn_mfma_f32_16x16x32_bf16(ah[ks], bl, acc, 0, 0, 0);
      acc = __builtin_amdgcn_mfma_f32_16x16x32_bf16(al[ks], bh, acc, 0, 0, 0);
    }
    int col = nt*16 + lrow;
    if (col < 900){
      float bb = bih[col];
      int rbase = gr0 + w*16 + lseg*4;
#pragma unroll
      for (int r=0;r<4;r++)
        gi[(size_t)(rbase + r)*900 + col] = acc[r] + bb;
    }
    if (nt < 56){
#pragma unroll
      for (int i=0;i<5;i++){
        int c = tid + i*256;
        int half = (c >= 640) ? 1 : 0; int cc = c - half*640;
        int row = cc/40, o16 = cc - row*40;
        ushort* dst = half ? Blo[buf^1] : Bhi[buf^1];
        *(uint4*)&dst[row*328 + o16*8] = pb[i];
      }
    }
    __syncthreads();
    buf ^= 1;
  }
}

// ---------------------------------------------------------------------------
// att score via bf16x3 MFMA: score[r] = sum_h ctx[h]*tanh((hs@W^T)[r][h]+b[h])
// A = hs rows (per-lane direct load + split), B = attW hi/lo (LDS dbuf).
// Epilogue: tanh+ctx per fragment col, 16-lane shfl reduce, no LDS trip.
// ---------------------------------------------------------------------------
__global__ __launch_bounds__(256,3) void att_mfma_kernel(
    const float* __restrict__ hs, const ushort* __restrict__ Whi,
    const ushort* __restrict__ Wlo, const float* __restrict__ bias,
    const float* __restrict__ ctx, float* __restrict__ score, int Rtot){
  __shared__ __align__(16) ushort Bhi[2][16*328];
  __shared__ __align__(16) ushort Blo[2][16*328];
  int tid = threadIdx.x;
  int r0 = blockIdx.x * 64;
  uint4 pb[5];
#pragma unroll
  for (int i=0;i<5;i++){
    int c = tid + i*256;
    int half = (c >= 640) ? 1 : 0; int cc = c - half*640;
    int row = cc/40, o16 = cc - row*40;
    const ushort* src = half ? Wlo : Whi;
    pb[i] = *(const uint4*)&src[(size_t)row*320 + o16*8];
  }
  int w = tid >> 6, L = tid & 63;
  int lrow = L & 15, lseg = L >> 4;
  int arow = r0 + w*16 + lrow;
  bool avalid = arow < Rtot;
  const float* aptr = hs + (size_t)(avalid ? arow : 0)*300;
  bf16x8 ah[10], al[10];
#pragma unroll
  for (int ks=0; ks<10; ks++){
    int k0 = ks*32 + lseg*8;
    float x[8];
    if (avalid && k0 + 8 <= 300){
      float4 v0 = *(const float4*)&aptr[k0];
      float4 v1 = *(const float4*)&aptr[k0+4];
      x[0]=v0.x; x[1]=v0.y; x[2]=v0.z; x[3]=v0.w;
      x[4]=v1.x; x[5]=v1.y; x[6]=v1.z; x[7]=v1.w;
    } else {
#pragma unroll
      for (int u=0;u<8;u++) x[u] = (avalid && k0+u < 300) ? aptr[k0+u] : 0.f;
    }
#pragma unroll
    for (int u=0;u<8;u++){
      ushort hb = f2bf_rne(x[u]);
      float lo = x[u] - __uint_as_float(((uint)hb)<<16);
      ah[ks][u] = (short)hb;
      al[ks][u] = (short)f2bf_rne(lo);
    }
  }
#pragma unroll
  for (int i=0;i<5;i++){
    int c = tid + i*256;
    int half = (c >= 640) ? 1 : 0; int cc = c - half*640;
    int row = cc/40, o16 = cc - row*40;
    ushort* dst = half ? Blo[0] : Bhi[0];
    *(uint4*)&dst[row*328 + o16*8] = pb[i];
  }
  __syncthreads();
  int buf = 0;
  int bfb = lrow*328 + lseg*8;
  float part[4] = {0.f,0.f,0.f,0.f};
  for (int nt = 0; nt < 19; ++nt){
    if (nt < 18){
#pragma unroll
      for (int i=0;i<5;i++){
        int c = tid + i*256;
        int half = (c >= 640) ? 1 : 0; int cc = c - half*640;
        int row = cc/40, o16 = cc - row*40;
        const ushort* src = half ? Wlo : Whi;
        pb[i] = *(const uint4*)&src[(size_t)((nt+1)*16 + row)*320 + o16*8];
      }
    }
    f32x4 acc = {0.f, 0.f, 0.f, 0.f};
#pragma unroll
    for (int ks=0; ks<10; ks++){
      bf16x8 bh = *(const bf16x8*)&Bhi[buf][bfb + ks*32];
      bf16x8 bl = *(const bf16x8*)&Blo[buf][bfb + ks*32];
      acc = __builtin_amdgcn_mfma_f32_16x16x32_bf16(ah[ks], bh, acc, 0, 0, 0);
      acc = __builtin_amdgcn_mfma_f32_16x16x32_bf16(ah[ks], bl, acc, 0, 0, 0);
      acc = __builtin_amdgcn_mfma_f32_16x16x32_bf16(al[ks], bh, acc, 0, 0, 0);
    }
    int col = nt*16 + lrow;
    if (col < 300){
      float bb = bias[col], cx = ctx[col];
#pragma unroll
      for (int r=0;r<4;r++) part[r] += cx * tanhf(acc[r] + bb);
    }
    if (nt < 18){
#pragma unroll
      for (int i=0;i<5;i++){
        int c = tid + i*256;
        int half = (c >= 640) ? 1 : 0; int cc = c - half*640;
        int row = cc/40, o16 = cc - row*40;
        ushort* dst = half ? Blo[buf^1] : Bhi[buf^1];
        *(uint4*)&dst[row*328 + o16*8] = pb[i];
      }
    }
    __syncthreads();
    buf ^= 1;
  }
#pragma unroll
  for (int off=1; off<16; off<<=1){
#pragma unroll
    for (int r=0;r<4;r++) part[r] += __shfl_xor(part[r], off);
  }
  if (lrow == 0){
    int rbase = r0 + w*16 + lseg*4;
#pragma unroll
    for (int r=0;r<4;r++)
      if (rbase + r < Rtot) score[rbase + r] = part[r];
  }
}

// sentence-level gi (tiny: 64 blocks, fp32)
__global__ __launch_bounds__(256) void sent_gi_kernel(
    const float* __restrict__ sv, const float* __restrict__ Wih,
    const float* __restrict__ bih, float* __restrict__ gi){
  __shared__ float A[16][G_];
  int r0 = blockIdx.x * 16;
  int s  = r0 >> 6;
  int bb_ = r0 & 63;
  for (int idx = threadIdx.x; idx < 16*75; idx += 256){
    int row = idx / 75, e4 = idx - row*75;
    *(float4*)&A[row][e4*4] =
        *(const float4*)&sv[(((size_t)(bb_+row))*S_ + s)*G_ + e4*4];
  }
  __syncthreads();
  int q = threadIdx.x;
  if (q >= 225) return;
  int j0 = q*4;
  const float4* w0 = (const float4*)(Wih + (size_t)(j0  )*G_);
  const float4* w1 = (const float4*)(Wih + (size_t)(j0+1)*G_);
  const float4* w2 = (const float4*)(Wih + (size_t)(j0+2)*G_);
  const float4* w3 = (const float4*)(Wih + (size_t)(j0+3)*G_);
  float acc[16][4];
#pragma unroll
  for (int i=0;i<16;i++){ acc[i][0]=0.f; acc[i][1]=0.f; acc[i][2]=0.f; acc[i][3]=0.f; }
  for (int e4=0; e4<75; e4++){
    float4 b0=w0[e4], b1=w1[e4], b2=w2[e4], b3=w3[e4];
#pragma unroll
    for (int i=0;i<16;i++){
      float4 av = *(const float4*)&A[i][e4*4];
      acc[i][0] += av.x*b0.x + av.y*b0.y + av.z*b0.z + av.w*b0.w;
      acc[i][1] += av.x*b1.x + av.y*b1.y + av.z*b1.z + av.w*b1.w;
      acc[i][2] += av.x*b2.x + av.y*b2.y + av.z*b2.z + av.w*b2.w;
      acc[i][3] += av.x*b3.x + av.y*b3.y + av.z*b3.z + av.w*b3.w;
    }
  }
  float4 bb = *(const float4*)&bih[j0];
#pragma unroll
  for (int i=0;i<16;i++){
    float4 o4;
    o4.x = acc[i][0]+bb.x; o4.y = acc[i][1]+bb.y;
    o4.z = acc[i][2]+bb.z; o4.w = acc[i][3]+bb.w;
    *(float4*)&gi[((size_t)(s*B_) + bb_ + i)*900 + j0] = o4;
  }
}

// ---------------------------------------------------------------------------
// GRU scan v5 (word): block = 8 rows x 1 dir, 768 threads (12 waves).
// GEMM threads tid<675: (j-pair j2, k-third kh); Wr[13][2] = 104 VGPR ->
// 3 waves/SIMD; each hl b128 read feeds 2 columns (LDS instr halved vs v4).
// Partials in ghp[3]; elementwise phase sums them; h_old read from hl[buf].
// ---------------------------------------------------------------------------
__global__ __launch_bounds__(768,3) void gru_scan_v5(
    const float* __restrict__ gi, const float* __restrict__ W5,
    const float* __restrict__ bhh, float* __restrict__ hs,
    int T, int N){
  int d  = blockIdx.y;
  int n0 = blockIdx.x * 8;
  __shared__ float hl[2][8][160];
  __shared__ float ghp[3][8][452];
  int tid = threadIdx.x;
  for (int idx = tid; idx < 2*8*160; idx += 768) (&hl[0][0][0])[idx] = 0.f;
  bool gact = tid < 675;
  int j2 = gact ? tid % 225 : 0;
  int kh = gact ? tid / 225 : 0;
  float4 Wr[13][2];
  {
    const float4* wb = (const float4*)(W5 + (size_t)(d*3 + kh)*13*225*8);
#pragma unroll
    for (int e4=0;e4<13;e4++){
      Wr[e4][0] = wb[(e4*225 + j2)*2 + 0];
      Wr[e4][1] = wb[(e4*225 + j2)*2 + 1];
    }
  }
  float b0 = 0.f, b1 = 0.f;
  if (gact && kh == 0){
    b0 = bhh[d*450 + 2*j2];
    b1 = bhh[d*450 + 2*j2 + 1];
  }
  int i0 = tid/150,        h0 = tid - i0*150;
  int u1 = tid + 768;
  int i1 = u1/150,         h1 = u1 - i1*150;
  bool e1 = u1 < 1200;
  int buf = 0;
  __syncthreads();
  for (int step = 0; step < T; ++step){
    int t = d ? (T-1-step) : step;
    const float* gib = gi + ((size_t)t*N + n0)*900 + d*450;
    // prefetch gi for elementwise phase (hidden under GEMM)
    float p0r = gib[(size_t)i0*900 + h0];
    float p0z = gib[(size_t)i0*900 + 150 + h0];
    float p0n = gib[(size_t)i0*900 + 300 + h0];
    float p1r=0.f, p1z=0.f, p1n=0.f;
    if (e1){
      p1r = gib[(size_t)i1*900 + h1];
      p1z = gib[(size_t)i1*900 + 150 + h1];
      p1n = gib[(size_t)i1*900 + 300 + h1];
    }
    if (gact){
      float a0[8], a1[8];
#pragma unroll
      for (int i=0;i<8;i++){ a0[i]=0.f; a1[i]=0.f; }
#pragma unroll
      for (int e4=0;e4<13;e4++){
        float4 w0 = Wr[e4][0], w1 = Wr[e4][1];
#pragma unroll
        for (int i=0;i<8;i++){
          float4 hv = *(const float4*)&hl[buf][i][(kh*13+e4)*4];
          a0[i] += w0.x*hv.x + w0.y*hv.y + w0.z*hv.z + w0.w*hv.w;
          a1[i] += w1.x*hv.x + w1.y*hv.y + w1.z*hv.z + w1.w*hv.w;
        }
      }
#pragma unroll
      for (int i=0;i<8;i++){
        float2 v; v.x = a0[i] + b0; v.y = a1[i] + b1;
        *(float2*)&ghp[kh][i][2*j2] = v;
      }
    }
    __syncthreads();
    {
      float ghr = ghp[0][i0][h0]     + ghp[1][i0][h0]     + ghp[2][i0][h0];
      float ghz = ghp[0][i0][150+h0] + ghp[1][i0][150+h0] + ghp[2][i0][150+h0];
      float ghn = ghp[0][i0][300+h0] + ghp[1][i0][300+h0] + ghp[2][i0][300+h0];
      float hold = hl[buf][i0][h0];
      float r  = sigm(p0r + ghr);
      float z  = sigm(p0z + ghz);
      float nn = tanhf(p0n + r*ghn);
      float h2 = (1.f - z)*nn + z*hold;
      hl[buf^1][i0][h0] = h2;
      hs[((size_t)t*N + n0 + i0)*G_ + d*H_ + h0] = h2;
    }
    if (e1){
      float ghr = ghp[0][i1][h1]     + ghp[1][i1][h1]     + ghp[2][i1][h1];
      float ghz = ghp[0][i1][150+h1] + ghp[1][i1][150+h1] + ghp[2][i1][150+h1];
      float ghn = ghp[0][i1][300+h1] + ghp[1][i1][300+h1] + ghp[2][i1][300+h1];
      float hold = hl[buf][i1][h1];
      float r  = sigm(p1r + ghr);
      float z  = sigm(p1z + ghz);
      float nn = tanhf(p1n + r*ghn);
      float h2 = (1.f - z)*nn + z*hold;
      hl[buf^1][i1][h1] = h2;
      hs[((size_t)t*N + n0 + i1)*G_ + d*H_ + h1] = h2;
    }
    buf ^= 1;
    __syncthreads();
  }
}

// ---------------------------------------------------------------------------
// GRU scan v4 (sentence, tiny): W in registers, fully unrolled
// ---------------------------------------------------------------------------
template<int R>
__global__ __launch_bounds__(512,2) void gru_scan_v4(
    const float* __restrict__ gi, const float* __restrict__ Wblk,
    const float* __restrict__ bhh, float* __restrict__ hs,
    int T, int N){
  int d  = blockIdx.y;
  int n0 = blockIdx.x * R;
  __shared__ float hl[2][R][152];
  __shared__ float gh[R][452];
  int tid = threadIdx.x;
  for (int idx = tid; idx < 2*R*152; idx += 512) (&hl[0][0][0])[idx] = 0.f;
  bool jact = tid < 450;
  bool hact = tid < 150;
  float4 Wr[38];
  float bj = 0.f;
  {
    const float4* Wb4 = (const float4*)(Wblk + (size_t)d*38*1800);
    int jj = jact ? tid : 0;
#pragma unroll
    for (int e4 = 0; e4 < 38; ++e4) Wr[e4] = Wb4[e4*450 + jj];
    if (jact) bj = bhh[d*450 + tid];
  }
  float hreg[R];
#pragma unroll
  for (int i=0;i<R;i++) hreg[i] = 0.f;
  int buf = 0;
  __syncthreads();
  for (int step = 0; step < T; ++step){
    int t = d ? (T-1-step) : step;
    const float* gib = gi + ((size_t)t*N + n0)*900 + d*450;
    float pre[R][3];
    if (hact){
#pragma unroll
      for (int i=0;i<R;i++){
        pre[i][0] = gib[(size_t)i*900 + tid];
        pre[i][1] = gib[(size_t)i*900 + 150 + tid];
        pre[i][2] = gib[(size_t)i*900 + 300 + tid];
      }
    }
    if (jact){
      float acc[R];
#pragma unroll
      for (int i=0;i<R;i++) acc[i] = 0.f;
#pragma unroll
      for (int e4 = 0; e4 < 38; ++e4){
        float4 w = Wr[e4];
#pragma unroll
        for (int i=0;i<R;i++){
          float4 hv = *(const float4*)&hl[buf][i][e4*4];
          acc[i] += w.x*hv.x + w.y*hv.y + w.z*hv.z + w.w*hv.w;
        }
      }
#pragma unroll
      for (int i=0;i<R;i++) gh[i][tid] = acc[i] + bj;
    }
    __syncthreads();
    if (hact){
#pragma unroll
      for (int i=0;i<R;i++){
        float r  = sigm(pre[i][0] + gh[i][tid]);
        float z  = sigm(pre[i][1] + gh[i][150+tid]);
        float nn = tanhf(pre[i][2] + r*gh[i][300+tid]);
        float h2 = (1.f - z)*nn + z*hreg[i];
        hreg[i] = h2;
        hl[buf^1][i][tid] = h2;
        hs[((size_t)t*N + n0 + i)*G_ + d*H_ + tid] = h2;
      }
    }
    buf ^= 1;
    __syncthreads();
  }
}

// softmax over t (per n) + weighted sum
__global__ __launch_bounds__(256) void att_combine_kernel(
    const float* __restrict__ score, const float* __restrict__ hs,
    float* __restrict__ out, int T, int N){
  int n = blockIdx.x;
  __shared__ float wa[64];
  if (threadIdx.x < T) wa[threadIdx.x] = score[threadIdx.x*N + n];
  __syncthreads();
  float m = -1e30f;
  for (int t=0;t<T;t++) m = fmaxf(m, wa[t]);
  float den = 0.f;
  for (int t=0;t<T;t++) den += __expf(wa[t]-m);
  float inv = 1.f/den;
  __syncthreads();
  if (threadIdx.x < T) wa[threadIdx.x] = __expf(wa[threadIdx.x]-m)*inv;
  __syncthreads();
  for (int g = threadIdx.x; g < G_; g += 256){
    float acc = 0.f;
    for (int t=0;t<T;t++) acc += wa[t] * hs[((size_t)t*N+n)*G_ + g];
    out[(size_t)n*G_ + g] = acc;
  }
}

// one wave per (b,k): both cosine sims
__global__ __launch_bounds__(256) void cossim_kernel(
    const int* __restrict__ cand, const int* __restrict__ sens,
    const float* __restrict__ ent, const float* __restrict__ sv,
    const float* __restrict__ odoc, float* __restrict__ sim){
  int w = (blockIdx.x*256 + threadIdx.x) >> 6;
  int lane = threadIdx.x & 63;
  if (w >= B_*NC_) return;
  int b = w / NC_, k = w - b*NC_;
  const float* c  = ent + (size_t)cand[b*NC_ + k]*E_;
  const float* a1 = sv  + ((size_t)b*S_ + sens[b])*G_;
  const float* a2 = odoc + (size_t)b*G_;
  float d1=0.f,d2=0.f,cc=0.f,n1=0.f,n2=0.f;
  for (int e = lane; e < E_; e += 64){
    float cv=c[e], v1=a1[e], v2=a2[e];
    d1+=v1*cv; d2+=v2*cv; cc+=cv*cv; n1+=v1*v1; n2+=v2*v2;
  }
  for (int off=32; off; off>>=1){
    d1+=__shfl_xor(d1,off); d2+=__shfl_xor(d2,off); cc+=__shfl_xor(cc,off);
    n1+=__shfl_xor(n1,off); n2+=__shfl_xor(n2,off);
  }
  if (lane == 0){
    float nc = sqrtf(cc);
    sim[(size_t)b*600 + k]       = d1 / fmaxf(sqrtf(n1)*nc, 1e-8f);
    sim[(size_t)b*600 + 300 + k] = d2 / fmaxf(sqrtf(n2)*nc, 1e-8f);
  }
}

// score = sim @ linW^T + linb; gold gather; argmax (first-max tie rule)
__global__ __launch_bounds__(256) void final_kernel(
    const float* __restrict__ sim, const float* __restrict__ linW,
    const float* __restrict__ linb, const int* __restrict__ idx,
    float* __restrict__ out){
  int b = blockIdx.x;
  __shared__ float ss[600];
  __shared__ float sc[300];
  __shared__ float bv[256];
  __shared__ int   bi[256];
  for (int j = threadIdx.x; j < 600; j += 256) ss[j] = sim[(size_t)b*600 + j];
  __syncthreads();
  float bestv = -1e30f; int besti = 0;
  for (int i = threadIdx.x; i < 300; i += 256){
    const float4* wr = (const float4*)(linW + (size_t)i*600);
    float acc = linb[i];
    for (int j4=0; j4<150; j4++){
      float4 w = wr[j4];
      int j = j4*4;
      acc += w.x*ss[j] + w.y*ss[j+1] + w.z*ss[j+2] + w.w*ss[j+3];
    }
    sc[i] = acc;
    out[64 + (size_t)b*300 + i] = acc;
    if (acc > bestv){ bestv = acc; besti = i; }
  }
  bv[threadIdx.x] = bestv; bi[threadIdx.x] = besti;
  __syncthreads();
  for (int s=128; s; s>>=1){
    if (threadIdx.x < s){
      float ov = bv[threadIdx.x+s]; int oi = bi[threadIdx.x+s];
      if (ov > bv[threadIdx.x] || (ov == bv[threadIdx.x] && oi < bi[threadIdx.x])){
        bv[threadIdx.x] = ov; bi[threadIdx.x] = oi;
      }
    }
    __syncthreads();
  }
  if (threadIdx.x == 0){
    out[b] = sc[idx[b]-1];
    out[64 + 64*300 + b] = (float)bi[0];
  }
}

extern "C" void kernel_launch(void* const* d_in, const int* in_sizes, int n_in,
                              void* d_out, int out_size, void* d_ws, size_t ws_size,
                              hipStream_t stream){
  const int*   docs  = (const int*)d_in[0];
  const int*   sens  = (const int*)d_in[1];
  const int*   cand  = (const int*)d_in[2];
  const int*   idx   = (const int*)d_in[3];
  const float* wemb  = (const float*)d_in[4];
  const float* eemb  = (const float*)d_in[5];
  const float* Wih_w = (const float*)d_in[6];
  const float* Whh_w = (const float*)d_in[7];
  const float* bih_w = (const float*)d_in[8];
  const float* bhh_w = (const float*)d_in[9];
  const float* attW_w= (const float*)d_in[10];
  const float* attb_w= (const float*)d_in[11];
  const float* ctx_w = (const float*)d_in[12];
  const float* Wih_s = (const float*)d_in[13];
  const float* Whh_s = (const float*)d_in[14];
  const float* bih_s = (const float*)d_in[15];
  const float* bhh_s = (const float*)d_in[16];
  const float* attW_s= (const float*)d_in[17];
  const float* attb_s= (const float*)d_in[18];
  const float* ctx_s = (const float*)d_in[19];
  const float* linW  = (const float*)d_in[20];
  const float* linb  = (const float*)d_in[21];

  float* ws = (float*)d_ws;
  size_t off = 0;
  float* gi_w    = ws + off; off += (size_t)T_*NW_*900;   // 176.9 MB
  float* hs_w    = ws + off; off += (size_t)T_*NW_*G_;    // 59 MB
  float* score_w = ws + off; off += (size_t)T_*NW_;
  float* sv      = ws + off; off += (size_t)NW_*G_;
  float* gi_s    = ws + off; off += (size_t)S_*B_*900;
  float* hs_s    = ws + off; off += (size_t)S_*B_*G_;
  float* score_s = ws + off; off += (size_t)S_*B_;
  float* odoc    = ws + off; off += (size_t)B_*G_;
  float* sim     = ws + off; off += (size_t)B_*600;
  float* Wblk_s  = ws + off; off += (size_t)2*38*450*4;   // sentence Whh tiles
  float* W5_w    = ws + off; off += (size_t)2*3*13*225*8; // word Whh v5 tiles
  ushort* Whi    = (ushort*)(ws + off); off += (size_t)912*320/2;
  ushort* Wlo    = (ushort*)(ws + off); off += (size_t)912*320/2;
  ushort* WAhi   = (ushort*)(ws + off); off += (size_t)304*320/2;
  ushort* WAlo   = (ushort*)(ws + off); off += (size_t)304*320/2;
  ushort* WShi   = (ushort*)(ws + off); off += (size_t)304*320/2;
  ushort* WSlo   = (ushort*)(ws + off); off += (size_t)304*320/2;

  float* out = (float*)d_out;

  // one-time weight preps
  prep_whh_kernel<<<(2*38*450*4+255)/256, 256, 0, stream>>>(Whh_s, Wblk_s);
  prep_whh_v5<<<(2*3*13*225*8+255)/256, 256, 0, stream>>>(Whh_w, W5_w);
  split_w_gen<<<912, 128, 0, stream>>>(Wih_w, Whi, Wlo, 900, 300, 320);
  split_w_gen<<<304, 128, 0, stream>>>(attW_w, WAhi, WAlo, 300, 300, 320);
  split_w_gen<<<304, 128, 0, stream>>>(attW_s, WShi, WSlo, 300, 300, 320);

  // word level
  gi_mfma_v2<<<RW_/64, 256, 0, stream>>>(docs, wemb, Whi, Wlo, bih_w, gi_w);
  gru_scan_v5<<<dim3(NW_/8, 2), 768, 0, stream>>>(gi_w, W5_w, bhh_w,
                                                  hs_w, T_, NW_);
  att_mfma_kernel<<<RW_/64, 256, 0, stream>>>(hs_w, WAhi, WAlo, attb_w,
                                              ctx_w, score_w, RW_);
  att_combine_kernel<<<NW_, 256, 0, stream>>>(score_w, hs_w, sv, T_, NW_);

  // sentence level
  sent_gi_kernel<<<RS_/16, 256, 0, stream>>>(sv, Wih_s, bih_s, gi_s);
  gru_scan_v4<2><<<dim3(B_/2, 2), 512, 0, stream>>>(gi_s, Wblk_s, bhh_s,
                                                    hs_s, S_, B_);
  att_mfma_kernel<<<RS_/64, 256, 0, stream>>>(hs_s, WShi, WSlo, attb_s,
                                              ctx_s, score_s, RS_);
  att_combine_kernel<<<B_, 256, 0, stream>>>(score_s, hs_s, odoc, S_, B_);

  // similarity + linear + gold + argmax
  cossim_kernel<<<(B_*NC_*64)/256, 256, 0, stream>>>(cand, sens, eemb, sv, odoc, sim);
  final_kernel<<<B_, 256, 0, stream>>>(sim, linW, linb, idx, out);
}

// Round 11
// 932.686 us; speedup vs baseline: 1.7199x; 1.0198x over previous
//
#include <hip/hip_runtime.h>
#include <hip/hip_bf16.h>
#include <math.h>

#define B_  64
#define S_  16
#define T_  48
#define E_  300
#define H_  150
#define G_  300   // 2H
#define NC_ 300
#define NW_ (B_*S_)     // 1024 word-level batch
#define RW_ (T_*NW_)    // 49152 word rows
#define RS_ (S_*B_)     // 1024 sentence rows
#define GST 912         // gi row stride (floats), 3648 B = 64B-aligned rows

typedef __attribute__((ext_vector_type(8))) short bf16x8;
typedef __attribute__((ext_vector_type(4))) float f32x4;

__device__ __forceinline__ float sigm(float x){ return 1.0f/(1.0f+__expf(-x)); }

__device__ __forceinline__ ushort f2bf_rne(float x){
  uint u = __float_as_uint(x);
  return (ushort)((u + 0x7FFFu + ((u>>16)&1u)) >> 16);
}

// ---------------------------------------------------------------------------
// Whh[2][450][150] -> Wblk[2][38][450][4], zero-padded (sentence gru v4)
// ---------------------------------------------------------------------------
__global__ __launch_bounds__(256) void prep_whh_kernel(
    const float* __restrict__ Whh, float* __restrict__ Wblk){
  int idx = blockIdx.x*256 + threadIdx.x;
  if (idx >= 2*38*450*4) return;
  int k  = idx & 3;
  int j  = (idx >> 2) % 450;
  int e4 = (idx >> 2) / 450 % 38;
  int d  = idx / (38*450*4);
  int e  = e4*4 + k;
  Wblk[idx] = (e < 150) ? Whh[((size_t)d*450 + j)*150 + e] : 0.f;
}

// ---------------------------------------------------------------------------
// Whh -> W5[d][kh(3)][e4(13)][j2(225)][c(2)][k(4)]  (word gru v5, zero-pad)
// ---------------------------------------------------------------------------
__global__ __launch_bounds__(256) void prep_whh_v5(
    const float* __restrict__ Whh, float* __restrict__ W5){
  int idx = blockIdx.x*256 + threadIdx.x;
  if (idx >= 2*3*13*225*8) return;
  int kk = idx & 3;
  int r1 = idx >> 2;
  int c  = r1 & 1;
  int r2 = r1 >> 1;
  int j2 = r2 % 225;
  int r3 = r2 / 225;
  int e4 = r3 % 13;
  int r4 = r3 / 13;
  int kh = r4 % 3;
  int d  = r4 / 3;
  int j  = j2*2 + c;
  int kg = (kh*13 + e4)*4 + kk;
  W5[idx] = (kg < 150) ? Whh[((size_t)d*450 + j)*150 + kg] : 0.f;
}

// ---------------------------------------------------------------------------
// generic fp32 -> bf16 hi/lo split: W[R][C] -> Whi/Wlo[gridDim.x][Cp]
// ---------------------------------------------------------------------------
__global__ __launch_bounds__(128) void split_w_gen(
    const float* __restrict__ W, ushort* __restrict__ Whi,
    ushort* __restrict__ Wlo, int R, int C, int Cp){
  int j = blockIdx.x;
  for (int k = threadIdx.x; k < Cp; k += 128){
    float x = (j < R && k < C) ? W[(size_t)j*C + k] : 0.f;
    ushort hb = f2bf_rne(x);
    float hf = __uint_as_float(((uint)hb)<<16);
    Whi[(size_t)j*Cp + k] = hb;
    Wlo[(size_t)j*Cp + k] = f2bf_rne(x - hf);
  }
}

// ---------------------------------------------------------------------------
// gi = X @ Wih^T + bih via bf16x3 MFMA. v3: gi rows padded to 912 floats so
// the 64B C-write chunks are sector-aligned (v2 paid 6.5x write amplification
// at stride 900: WRITE_SIZE 1.147 GB for a 177 MB buffer).
// ---------------------------------------------------------------------------
__global__ __launch_bounds__(256,3) void gi_mfma_v2(
    const int* __restrict__ docs, const float* __restrict__ emb,
    const ushort* __restrict__ Whi, const ushort* __restrict__ Wlo,
    const float* __restrict__ bih, float* __restrict__ gi){
  __shared__ __align__(16) ushort Bhi[2][16*328];
  __shared__ __align__(16) ushort Blo[2][16*328];
  __shared__ int toks[64];
  int tid = threadIdx.x;
  int gr0 = blockIdx.x * 64;
  int t  = gr0 >> 10;
  int n0 = gr0 & 1023;
  if (tid < 64) toks[tid] = docs[(n0 + tid)*T_ + t];
  uint4 pb[5];
#pragma unroll
  for (int i=0;i<5;i++){
    int c = tid + i*256;
    int half = (c >= 640) ? 1 : 0; int cc = c - half*640;
    int row = cc/40, o16 = cc - row*40;
    const ushort* src = half ? Wlo : Whi;
    pb[i] = *(const uint4*)&src[(size_t)row*320 + o16*8];
  }
  __syncthreads();   // toks visible
  int w = tid >> 6, L = tid & 63;
  int lrow = L & 15, lseg = L >> 4;
  const float* aptr = emb + (size_t)toks[w*16 + lrow]*300;
  bf16x8 ah[10], al[10];
#pragma unroll
  for (int ks=0; ks<10; ks++){
    int k0 = ks*32 + lseg*8;
    float x[8];
    if (k0 + 8 <= 300){
      float4 v0 = *(const float4*)&aptr[k0];
      float4 v1 = *(const float4*)&aptr[k0+4];
      x[0]=v0.x; x[1]=v0.y; x[2]=v0.z; x[3]=v0.w;
      x[4]=v1.x; x[5]=v1.y; x[6]=v1.z; x[7]=v1.w;
    } else {
#pragma unroll
      for (int u=0;u<8;u++) x[u] = (k0+u < 300) ? aptr[k0+u] : 0.f;
    }
#pragma unroll
    for (int u=0;u<8;u++){
      ushort hb = f2bf_rne(x[u]);
      float lo = x[u] - __uint_as_float(((uint)hb)<<16);
      ah[ks][u] = (short)hb;
      al[ks][u] = (short)f2bf_rne(lo);
    }
  }
#pragma unroll
  for (int i=0;i<5;i++){
    int c = tid + i*256;
    int half = (c >= 640) ? 1 : 0; int cc = c - half*640;
    int row = cc/40, o16 = cc - row*40;
    ushort* dst = half ? Blo[0] : Bhi[0];
    *(uint4*)&dst[row*328 + o16*8] = pb[i];
  }
  __syncthreads();
  int buf = 0;
  int bfb = lrow*328 + lseg*8;
  for (int nt = 0; nt < 57; ++nt){
    if (nt < 56){
#pragma unroll
      for (int i=0;i<5;i++){
        int c = tid + i*256;
        int half = (c >= 640) ? 1 : 0; int cc = c - half*640;
        int row = cc/40, o16 = cc - row*40;
        const ushort* src = half ? Wlo : Whi;
        pb[i] = *(const uint4*)&src[(size_t)((nt+1)*16 + row)*320 + o16*8];
      }
    }
    f32x4 acc = {0.f, 0.f, 0.f, 0.f};
#pragma unroll
    for (int ks=0; ks<10; ks++){
      bf16x8 bh = *(const bf16x8*)&Bhi[buf][bfb + ks*32];
      bf16x8 bl = *(const bf16x8*)&Blo[buf][bfb + ks*32];
      acc = __builtin_amdgcn_mfma_f32_16x16x32_bf16(ah[ks], bh, acc, 0, 0, 0);
      acc = __builtin_amdgcn_mfma_f32_16x16x32_bf16(ah[ks], bl, acc, 0, 0, 0);
      acc = __builtin_amdgcn_mfma_f32_16x16x32_bf16(al[ks], bh, acc, 0, 0, 0);
    }
    int col = nt*16 + lrow;
    if (col < 900){
      float bb = bih[col];
      int rbase = gr0 + w*16 + lseg*4;
#pragma unroll
      for (int r=0;r<4;r++)
        gi[(size_t)(rbase + r)*GST + col] = acc[r] + bb;
    }
    if (nt < 56){
#pragma unroll
      for (int i=0;i<5;i++){
        int c = tid + i*256;
        int half = (c >= 640) ? 1 : 0; int cc = c - half*640;
        int row = cc/40, o16 = cc - row*40;
        ushort* dst = half ? Blo[buf^1] : Bhi[buf^1];
        *(uint4*)&dst[row*328 + o16*8] = pb[i];
      }
    }
    __syncthreads();
    buf ^= 1;
  }
}

// ---------------------------------------------------------------------------
// att score via bf16x3 MFMA (writes only score — no layout issue)
// ---------------------------------------------------------------------------
__global__ __launch_bounds__(256,3) void att_mfma_kernel(
    const float* __restrict__ hs, const ushort* __restrict__ Whi,
    const ushort* __restrict__ Wlo, const float* __restrict__ bias,
    const float* __restrict__ ctx, float* __restrict__ score, int Rtot){
  __shared__ __align__(16) ushort Bhi[2][16*328];
  __shared__ __align__(16) ushort Blo[2][16*328];
  int tid = threadIdx.x;
  int r0 = blockIdx.x * 64;
  uint4 pb[5];
#pragma unroll
  for (int i=0;i<5;i++){
    int c = tid + i*256;
    int half = (c >= 640) ? 1 : 0; int cc = c - half*640;
    int row = cc/40, o16 = cc - row*40;
    const ushort* src = half ? Wlo : Whi;
    pb[i] = *(const uint4*)&src[(size_t)row*320 + o16*8];
  }
  int w = tid >> 6, L = tid & 63;
  int lrow = L & 15, lseg = L >> 4;
  int arow = r0 + w*16 + lrow;
  bool avalid = arow < Rtot;
  const float* aptr = hs + (size_t)(avalid ? arow : 0)*300;
  bf16x8 ah[10], al[10];
#pragma unroll
  for (int ks=0; ks<10; ks++){
    int k0 = ks*32 + lseg*8;
    float x[8];
    if (avalid && k0 + 8 <= 300){
      float4 v0 = *(const float4*)&aptr[k0];
      float4 v1 = *(const float4*)&aptr[k0+4];
      x[0]=v0.x; x[1]=v0.y; x[2]=v0.z; x[3]=v0.w;
      x[4]=v1.x; x[5]=v1.y; x[6]=v1.z; x[7]=v1.w;
    } else {
#pragma unroll
      for (int u=0;u<8;u++) x[u] = (avalid && k0+u < 300) ? aptr[k0+u] : 0.f;
    }
#pragma unroll
    for (int u=0;u<8;u++){
      ushort hb = f2bf_rne(x[u]);
      float lo = x[u] - __uint_as_float(((uint)hb)<<16);
      ah[ks][u] = (short)hb;
      al[ks][u] = (short)f2bf_rne(lo);
    }
  }
#pragma unroll
  for (int i=0;i<5;i++){
    int c = tid + i*256;
    int half = (c >= 640) ? 1 : 0; int cc = c - half*640;
    int row = cc/40, o16 = cc - row*40;
    ushort* dst = half ? Blo[0] : Bhi[0];
    *(uint4*)&dst[row*328 + o16*8] = pb[i];
  }
  __syncthreads();
  int buf = 0;
  int bfb = lrow*328 + lseg*8;
  float part[4] = {0.f,0.f,0.f,0.f};
  for (int nt = 0; nt < 19; ++nt){
    if (nt < 18){
#pragma unroll
      for (int i=0;i<5;i++){
        int c = tid + i*256;
        int half = (c >= 640) ? 1 : 0; int cc = c - half*640;
        int row = cc/40, o16 = cc - row*40;
        const ushort* src = half ? Wlo : Whi;
        pb[i] = *(const uint4*)&src[(size_t)((nt+1)*16 + row)*320 + o16*8];
      }
    }
    f32x4 acc = {0.f, 0.f, 0.f, 0.f};
#pragma unroll
    for (int ks=0; ks<10; ks++){
      bf16x8 bh = *(const bf16x8*)&Bhi[buf][bfb + ks*32];
      bf16x8 bl = *(const bf16x8*)&Blo[buf][bfb + ks*32];
      acc = __builtin_amdgcn_mfma_f32_16x16x32_bf16(ah[ks], bh, acc, 0, 0, 0);
      acc = __builtin_amdgcn_mfma_f32_16x16x32_bf16(ah[ks], bl, acc, 0, 0, 0);
      acc = __builtin_amdgcn_mfma_f32_16x16x32_bf16(al[ks], bh, acc, 0, 0, 0);
    }
    int col = nt*16 + lrow;
    if (col < 300){
      float bb = bias[col], cx = ctx[col];
#pragma unroll
      for (int r=0;r<4;r++) part[r] += cx * tanhf(acc[r] + bb);
    }
    if (nt < 18){
#pragma unroll
      for (int i=0;i<5;i++){
        int c = tid + i*256;
        int half = (c >= 640) ? 1 : 0; int cc = c - half*640;
        int row = cc/40, o16 = cc - row*40;
        ushort* dst = half ? Blo[buf^1] : Bhi[buf^1];
        *(uint4*)&dst[row*328 + o16*8] = pb[i];
      }
    }
    __syncthreads();
    buf ^= 1;
  }
#pragma unroll
  for (int off=1; off<16; off<<=1){
#pragma unroll
    for (int r=0;r<4;r++) part[r] += __shfl_xor(part[r], off);
  }
  if (lrow == 0){
    int rbase = r0 + w*16 + lseg*4;
#pragma unroll
    for (int r=0;r<4;r++)
      if (rbase + r < Rtot) score[rbase + r] = part[r];
  }
}

// sentence-level gi (tiny: 64 blocks, fp32), stride GST
__global__ __launch_bounds__(256) void sent_gi_kernel(
    const float* __restrict__ sv, const float* __restrict__ Wih,
    const float* __restrict__ bih, float* __restrict__ gi){
  __shared__ float A[16][G_];
  int r0 = blockIdx.x * 16;
  int s  = r0 >> 6;
  int bb_ = r0 & 63;
  for (int idx = threadIdx.x; idx < 16*75; idx += 256){
    int row = idx / 75, e4 = idx - row*75;
    *(float4*)&A[row][e4*4] =
        *(const float4*)&sv[(((size_t)(bb_+row))*S_ + s)*G_ + e4*4];
  }
  __syncthreads();
  int q = threadIdx.x;
  if (q >= 225) return;
  int j0 = q*4;
  const float4* w0 = (const float4*)(Wih + (size_t)(j0  )*G_);
  const float4* w1 = (const float4*)(Wih + (size_t)(j0+1)*G_);
  const float4* w2 = (const float4*)(Wih + (size_t)(j0+2)*G_);
  const float4* w3 = (const float4*)(Wih + (size_t)(j0+3)*G_);
  float acc[16][4];
#pragma unroll
  for (int i=0;i<16;i++){ acc[i][0]=0.f; acc[i][1]=0.f; acc[i][2]=0.f; acc[i][3]=0.f; }
  for (int e4=0; e4<75; e4++){
    float4 b0=w0[e4], b1=w1[e4], b2=w2[e4], b3=w3[e4];
#pragma unroll
    for (int i=0;i<16;i++){
      float4 av = *(const float4*)&A[i][e4*4];
      acc[i][0] += av.x*b0.x + av.y*b0.y + av.z*b0.z + av.w*b0.w;
      acc[i][1] += av.x*b1.x + av.y*b1.y + av.z*b1.z + av.w*b1.w;
      acc[i][2] += av.x*b2.x + av.y*b2.y + av.z*b2.z + av.w*b2.w;
      acc[i][3] += av.x*b3.x + av.y*b3.y + av.z*b3.z + av.w*b3.w;
    }
  }
  float4 bb = *(const float4*)&bih[j0];
#pragma unroll
  for (int i=0;i<16;i++){
    float4 o4;
    o4.x = acc[i][0]+bb.x; o4.y = acc[i][1]+bb.y;
    o4.z = acc[i][2]+bb.z; o4.w = acc[i][3]+bb.w;
    *(float4*)&gi[((size_t)(s*B_) + bb_ + i)*GST + j0] = o4;
  }
}

// ---------------------------------------------------------------------------
// GRU scan v5 (word): gi stride GST
// ---------------------------------------------------------------------------
__global__ __launch_bounds__(768,3) void gru_scan_v5(
    const float* __restrict__ gi, const float* __restrict__ W5,
    const float* __restrict__ bhh, float* __restrict__ hs,
    int T, int N){
  int d  = blockIdx.y;
  int n0 = blockIdx.x * 8;
  __shared__ float hl[2][8][160];
  __shared__ float ghp[3][8][452];
  int tid = threadIdx.x;
  for (int idx = tid; idx < 2*8*160; idx += 768) (&hl[0][0][0])[idx] = 0.f;
  bool gact = tid < 675;
  int j2 = gact ? tid % 225 : 0;
  int kh = gact ? tid / 225 : 0;
  float4 Wr[13][2];
  {
    const float4* wb = (const float4*)(W5 + (size_t)(d*3 + kh)*13*225*8);
#pragma unroll
    for (int e4=0;e4<13;e4++){
      Wr[e4][0] = wb[(e4*225 + j2)*2 + 0];
      Wr[e4][1] = wb[(e4*225 + j2)*2 + 1];
    }
  }
  float b0 = 0.f, b1 = 0.f;
  if (gact && kh == 0){
    b0 = bhh[d*450 + 2*j2];
    b1 = bhh[d*450 + 2*j2 + 1];
  }
  int i0 = tid/150,        h0 = tid - i0*150;
  int u1 = tid + 768;
  int i1 = u1/150,         h1 = u1 - i1*150;
  bool e1 = u1 < 1200;
  int buf = 0;
  __syncthreads();
  for (int step = 0; step < T; ++step){
    int t = d ? (T-1-step) : step;
    const float* gib = gi + ((size_t)t*N + n0)*GST + d*450;
    float p0r = gib[(size_t)i0*GST + h0];
    float p0z = gib[(size_t)i0*GST + 150 + h0];
    float p0n = gib[(size_t)i0*GST + 300 + h0];
    float p1r=0.f, p1z=0.f, p1n=0.f;
    if (e1){
      p1r = gib[(size_t)i1*GST + h1];
      p1z = gib[(size_t)i1*GST + 150 + h1];
      p1n = gib[(size_t)i1*GST + 300 + h1];
    }
    if (gact){
      float a0[8], a1[8];
#pragma unroll
      for (int i=0;i<8;i++){ a0[i]=0.f; a1[i]=0.f; }
#pragma unroll
      for (int e4=0;e4<13;e4++){
        float4 w0 = Wr[e4][0], w1 = Wr[e4][1];
#pragma unroll
        for (int i=0;i<8;i++){
          float4 hv = *(const float4*)&hl[buf][i][(kh*13+e4)*4];
          a0[i] += w0.x*hv.x + w0.y*hv.y + w0.z*hv.z + w0.w*hv.w;
          a1[i] += w1.x*hv.x + w1.y*hv.y + w1.z*hv.z + w1.w*hv.w;
        }
      }
#pragma unroll
      for (int i=0;i<8;i++){
        float2 v; v.x = a0[i] + b0; v.y = a1[i] + b1;
        *(float2*)&ghp[kh][i][2*j2] = v;
      }
    }
    __syncthreads();
    {
      float ghr = ghp[0][i0][h0]     + ghp[1][i0][h0]     + ghp[2][i0][h0];
      float ghz = ghp[0][i0][150+h0] + ghp[1][i0][150+h0] + ghp[2][i0][150+h0];
      float ghn = ghp[0][i0][300+h0] + ghp[1][i0][300+h0] + ghp[2][i0][300+h0];
      float hold = hl[buf][i0][h0];
      float r  = sigm(p0r + ghr);
      float z  = sigm(p0z + ghz);
      float nn = tanhf(p0n + r*ghn);
      float h2 = (1.f - z)*nn + z*hold;
      hl[buf^1][i0][h0] = h2;
      hs[((size_t)t*N + n0 + i0)*G_ + d*H_ + h0] = h2;
    }
    if (e1){
      float ghr = ghp[0][i1][h1]     + ghp[1][i1][h1]     + ghp[2][i1][h1];
      float ghz = ghp[0][i1][150+h1] + ghp[1][i1][150+h1] + ghp[2][i1][150+h1];
      float ghn = ghp[0][i1][300+h1] + ghp[1][i1][300+h1] + ghp[2][i1][300+h1];
      float hold = hl[buf][i1][h1];
      float r  = sigm(p1r + ghr);
      float z  = sigm(p1z + ghz);
      float nn = tanhf(p1n + r*ghn);
      float h2 = (1.f - z)*nn + z*hold;
      hl[buf^1][i1][h1] = h2;
      hs[((size_t)t*N + n0 + i1)*G_ + d*H_ + h1] = h2;
    }
    buf ^= 1;
    __syncthreads();
  }
}

// ---------------------------------------------------------------------------
// GRU scan v4 (sentence, tiny): gi stride GST
// ---------------------------------------------------------------------------
template<int R>
__global__ __launch_bounds__(512,2) void gru_scan_v4(
    const float* __restrict__ gi, const float* __restrict__ Wblk,
    const float* __restrict__ bhh, float* __restrict__ hs,
    int T, int N){
  int d  = blockIdx.y;
  int n0 = blockIdx.x * R;
  __shared__ float hl[2][R][152];
  __shared__ float gh[R][452];
  int tid = threadIdx.x;
  for (int idx = tid; idx < 2*R*152; idx += 512) (&hl[0][0][0])[idx] = 0.f;
  bool jact = tid < 450;
  bool hact = tid < 150;
  float4 Wr[38];
  float bj = 0.f;
  {
    const float4* Wb4 = (const float4*)(Wblk + (size_t)d*38*1800);
    int jj = jact ? tid : 0;
#pragma unroll
    for (int e4 = 0; e4 < 38; ++e4) Wr[e4] = Wb4[e4*450 + jj];
    if (jact) bj = bhh[d*450 + tid];
  }
  float hreg[R];
#pragma unroll
  for (int i=0;i<R;i++) hreg[i] = 0.f;
  int buf = 0;
  __syncthreads();
  for (int step = 0; step < T; ++step){
    int t = d ? (T-1-step) : step;
    const float* gib = gi + ((size_t)t*N + n0)*GST + d*450;
    float pre[R][3];
    if (hact){
#pragma unroll
      for (int i=0;i<R;i++){
        pre[i][0] = gib[(size_t)i*GST + tid];
        pre[i][1] = gib[(size_t)i*GST + 150 + tid];
        pre[i][2] = gib[(size_t)i*GST + 300 + tid];
      }
    }
    if (jact){
      float acc[R];
#pragma unroll
      for (int i=0;i<R;i++) acc[i] = 0.f;
#pragma unroll
      for (int e4 = 0; e4 < 38; ++e4){
        float4 w = Wr[e4];
#pragma unroll
        for (int i=0;i<R;i++){
          float4 hv = *(const float4*)&hl[buf][i][e4*4];
          acc[i] += w.x*hv.x + w.y*hv.y + w.z*hv.z + w.w*hv.w;
        }
      }
#pragma unroll
      for (int i=0;i<R;i++) gh[i][tid] = acc[i] + bj;
    }
    __syncthreads();
    if (hact){
#pragma unroll
      for (int i=0;i<R;i++){
        float r  = sigm(pre[i][0] + gh[i][tid]);
        float z  = sigm(pre[i][1] + gh[i][150+tid]);
        float nn = tanhf(pre[i][2] + r*gh[i][300+tid]);
        float h2 = (1.f - z)*nn + z*hreg[i];
        hreg[i] = h2;
        hl[buf^1][i][tid] = h2;
        hs[((size_t)t*N + n0 + i)*G_ + d*H_ + tid] = h2;
      }
    }
    buf ^= 1;
    __syncthreads();
  }
}

// softmax over t (per n) + weighted sum
__global__ __launch_bounds__(256) void att_combine_kernel(
    const float* __restrict__ score, const float* __restrict__ hs,
    float* __restrict__ out, int T, int N){
  int n = blockIdx.x;
  __shared__ float wa[64];
  if (threadIdx.x < T) wa[threadIdx.x] = score[threadIdx.x*N + n];
  __syncthreads();
  float m = -1e30f;
  for (int t=0;t<T;t++) m = fmaxf(m, wa[t]);
  float den = 0.f;
  for (int t=0;t<T;t++) den += __expf(wa[t]-m);
  float inv = 1.f/den;
  __syncthreads();
  if (threadIdx.x < T) wa[threadIdx.x] = __expf(wa[threadIdx.x]-m)*inv;
  __syncthreads();
  for (int g = threadIdx.x; g < G_; g += 256){
    float acc = 0.f;
    for (int t=0;t<T;t++) acc += wa[t] * hs[((size_t)t*N+n)*G_ + g];
    out[(size_t)n*G_ + g] = acc;
  }
}

// one wave per (b,k): both cosine sims
__global__ __launch_bounds__(256) void cossim_kernel(
    const int* __restrict__ cand, const int* __restrict__ sens,
    const float* __restrict__ ent, const float* __restrict__ sv,
    const float* __restrict__ odoc, float* __restrict__ sim){
  int w = (blockIdx.x*256 + threadIdx.x) >> 6;
  int lane = threadIdx.x & 63;
  if (w >= B_*NC_) return;
  int b = w / NC_, k = w - b*NC_;
  const float* c  = ent + (size_t)cand[b*NC_ + k]*E_;
  const float* a1 = sv  + ((size_t)b*S_ + sens[b])*G_;
  const float* a2 = odoc + (size_t)b*G_;
  float d1=0.f,d2=0.f,cc=0.f,n1=0.f,n2=0.f;
  for (int e = lane; e < E_; e += 64){
    float cv=c[e], v1=a1[e], v2=a2[e];
    d1+=v1*cv; d2+=v2*cv; cc+=cv*cv; n1+=v1*v1; n2+=v2*v2;
  }
  for (int off=32; off; off>>=1){
    d1+=__shfl_xor(d1,off); d2+=__shfl_xor(d2,off); cc+=__shfl_xor(cc,off);
    n1+=__shfl_xor(n1,off); n2+=__shfl_xor(n2,off);
  }
  if (lane == 0){
    float nc = sqrtf(cc);
    sim[(size_t)b*600 + k]       = d1 / fmaxf(sqrtf(n1)*nc, 1e-8f);
    sim[(size_t)b*600 + 300 + k] = d2 / fmaxf(sqrtf(n2)*nc, 1e-8f);
  }
}

// score = sim @ linW^T + linb; gold gather; argmax (first-max tie rule)
__global__ __launch_bounds__(256) void final_kernel(
    const float* __restrict__ sim, const float* __restrict__ linW,
    const float* __restrict__ linb, const int* __restrict__ idx,
    float* __restrict__ out){
  int b = blockIdx.x;
  __shared__ float ss[600];
  __shared__ float sc[300];
  __shared__ float bv[256];
  __shared__ int   bi[256];
  for (int j = threadIdx.x; j < 600; j += 256) ss[j] = sim[(size_t)b*600 + j];
  __syncthreads();
  float bestv = -1e30f; int besti = 0;
  for (int i = threadIdx.x; i < 300; i += 256){
    const float4* wr = (const float4*)(linW + (size_t)i*600);
    float acc = linb[i];
    for (int j4=0; j4<150; j4++){
      float4 w = wr[j4];
      int j = j4*4;
      acc += w.x*ss[j] + w.y*ss[j+1] + w.z*ss[j+2] + w.w*ss[j+3];
    }
    sc[i] = acc;
    out[64 + (size_t)b*300 + i] = acc;
    if (acc > bestv){ bestv = acc; besti = i; }
  }
  bv[threadIdx.x] = bestv; bi[threadIdx.x] = besti;
  __syncthreads();
  for (int s=128; s; s>>=1){
    if (threadIdx.x < s){
      float ov = bv[threadIdx.x+s]; int oi = bi[threadIdx.x+s];
      if (ov > bv[threadIdx.x] || (ov == bv[threadIdx.x] && oi < bi[threadIdx.x])){
        bv[threadIdx.x] = ov; bi[threadIdx.x] = oi;
      }
    }
    __syncthreads();
  }
  if (threadIdx.x == 0){
    out[b] = sc[idx[b]-1];
    out[64 + 64*300 + b] = (float)bi[0];
  }
}

extern "C" void kernel_launch(void* const* d_in, const int* in_sizes, int n_in,
                              void* d_out, int out_size, void* d_ws, size_t ws_size,
                              hipStream_t stream){
  const int*   docs  = (const int*)d_in[0];
  const int*   sens  = (const int*)d_in[1];
  const int*   cand  = (const int*)d_in[2];
  const int*   idx   = (const int*)d_in[3];
  const float* wemb  = (const float*)d_in[4];
  const float* eemb  = (const float*)d_in[5];
  const float* Wih_w = (const float*)d_in[6];
  const float* Whh_w = (const float*)d_in[7];
  const float* bih_w = (const float*)d_in[8];
  const float* bhh_w = (const float*)d_in[9];
  const float* attW_w= (const float*)d_in[10];
  const float* attb_w= (const float*)d_in[11];
  const float* ctx_w = (const float*)d_in[12];
  const float* Wih_s = (const float*)d_in[13];
  const float* Whh_s = (const float*)d_in[14];
  const float* bih_s = (const float*)d_in[15];
  const float* bhh_s = (const float*)d_in[16];
  const float* attW_s= (const float*)d_in[17];
  const float* attb_s= (const float*)d_in[18];
  const float* ctx_s = (const float*)d_in[19];
  const float* linW  = (const float*)d_in[20];
  const float* linb  = (const float*)d_in[21];

  float* ws = (float*)d_ws;
  size_t off = 0;
  float* gi_w    = ws + off; off += (size_t)T_*NW_*GST;   // 179 MB (padded)
  float* hs_w    = ws + off; off += (size_t)T_*NW_*G_;    // 59 MB
  float* score_w = ws + off; off += (size_t)T_*NW_;
  float* sv      = ws + off; off += (size_t)NW_*G_;
  float* gi_s    = ws + off; off += (size_t)S_*B_*GST;
  float* hs_s    = ws + off; off += (size_t)S_*B_*G_;
  float* score_s = ws + off; off += (size_t)S_*B_;
  float* odoc    = ws + off; off += (size_t)B_*G_;
  float* sim     = ws + off; off += (size_t)B_*600;
  float* Wblk_s  = ws + off; off += (size_t)2*38*450*4;   // sentence Whh tiles
  float* W5_w    = ws + off; off += (size_t)2*3*13*225*8; // word Whh v5 tiles
  ushort* Whi    = (ushort*)(ws + off); off += (size_t)912*320/2;
  ushort* Wlo    = (ushort*)(ws + off); off += (size_t)912*320/2;
  ushort* WAhi   = (ushort*)(ws + off); off += (size_t)304*320/2;
  ushort* WAlo   = (ushort*)(ws + off); off += (size_t)304*320/2;
  ushort* WShi   = (ushort*)(ws + off); off += (size_t)304*320/2;
  ushort* WSlo   = (ushort*)(ws + off); off += (size_t)304*320/2;

  float* out = (float*)d_out;

  // one-time weight preps
  prep_whh_kernel<<<(2*38*450*4+255)/256, 256, 0, stream>>>(Whh_s, Wblk_s);
  prep_whh_v5<<<(2*3*13*225*8+255)/256, 256, 0, stream>>>(Whh_w, W5_w);
  split_w_gen<<<912, 128, 0, stream>>>(Wih_w, Whi, Wlo, 900, 300, 320);
  split_w_gen<<<304, 128, 0, stream>>>(attW_w, WAhi, WAlo, 300, 300, 320);
  split_w_gen<<<304, 128, 0, stream>>>(attW_s, WShi, WSlo, 300, 300, 320);

  // word level
  gi_mfma_v2<<<RW_/64, 256, 0, stream>>>(docs, wemb, Whi, Wlo, bih_w, gi_w);
  gru_scan_v5<<<dim3(NW_/8, 2), 768, 0, stream>>>(gi_w, W5_w, bhh_w,
                                                  hs_w, T_, NW_);
  att_mfma_kernel<<<RW_/64, 256, 0, stream>>>(hs_w, WAhi, WAlo, attb_w,
                                              ctx_w, score_w, RW_);
  att_combine_kernel<<<NW_, 256, 0, stream>>>(score_w, hs_w, sv, T_, NW_);

  // sentence level
  sent_gi_kernel<<<RS_/16, 256, 0, stream>>>(sv, Wih_s, bih_s, gi_s);
  gru_scan_v4<2><<<dim3(B_/2, 2), 512, 0, stream>>>(gi_s, Wblk_s, bhh_s,
                                                    hs_s, S_, B_);
  att_mfma_kernel<<<RS_/64, 256, 0, stream>>>(hs_s, WShi, WSlo, attb_s,
                                              ctx_s, score_s, RS_);
  att_combine_kernel<<<B_, 256, 0, stream>>>(score_s, hs_s, odoc, S_, B_);

  // similarity + linear + gold + argmax
  cossim_kernel<<<(B_*NC_*64)/256, 256, 0, stream>>>(cand, sens, eemb, sv, odoc, sim);
  final_kernel<<<B_, 256, 0, stream>>>(sim, linW, linb, idx, out);
}

// Round 12
// 799.499 us; speedup vs baseline: 2.0064x; 1.1666x over previous
//
#include <hip/hip_runtime.h>
#include <hip/hip_bf16.h>
#include <math.h>

#define B_  64
#define S_  16
#define T_  48
#define E_  300
#define H_  150
#define G_  300   // 2H
#define NC_ 300
#define NW_ (B_*S_)     // 1024 word-level batch
#define RW_ (T_*NW_)    // 49152 word rows
#define RS_ (S_*B_)     // 1024 sentence rows
#define GST 960         // gi row stride (floats): 3840 B = 15x256 B aligned rows

typedef __attribute__((ext_vector_type(8))) short bf16x8;
typedef __attribute__((ext_vector_type(4))) float f32x4;

__device__ __forceinline__ float sigm(float x){ return 1.0f/(1.0f+__expf(-x)); }

__device__ __forceinline__ ushort f2bf_rne(float x){
  uint u = __float_as_uint(x);
  return (ushort)((u + 0x7FFFu + ((u>>16)&1u)) >> 16);
}

// ---------------------------------------------------------------------------
// Whh[2][450][150] -> Wblk[2][38][450][4], zero-padded (sentence gru v4)
// ---------------------------------------------------------------------------
__global__ __launch_bounds__(256) void prep_whh_kernel(
    const float* __restrict__ Whh, float* __restrict__ Wblk){
  int idx = blockIdx.x*256 + threadIdx.x;
  if (idx >= 2*38*450*4) return;
  int k  = idx & 3;
  int j  = (idx >> 2) % 450;
  int e4 = (idx >> 2) / 450 % 38;
  int d  = idx / (38*450*4);
  int e  = e4*4 + k;
  Wblk[idx] = (e < 150) ? Whh[((size_t)d*450 + j)*150 + e] : 0.f;
}

// ---------------------------------------------------------------------------
// Whh -> W5[d][kh(3)][e4(13)][j2(225)][c(2)][k(4)]  (word gru v5, zero-pad)
// ---------------------------------------------------------------------------
__global__ __launch_bounds__(256) void prep_whh_v5(
    const float* __restrict__ Whh, float* __restrict__ W5){
  int idx = blockIdx.x*256 + threadIdx.x;
  if (idx >= 2*3*13*225*8) return;
  int kk = idx & 3;
  int r1 = idx >> 2;
  int c  = r1 & 1;
  int r2 = r1 >> 1;
  int j2 = r2 % 225;
  int r3 = r2 / 225;
  int e4 = r3 % 13;
  int r4 = r3 / 13;
  int kh = r4 % 3;
  int d  = r4 / 3;
  int j  = j2*2 + c;
  int kg = (kh*13 + e4)*4 + kk;
  W5[idx] = (kg < 150) ? Whh[((size_t)d*450 + j)*150 + kg] : 0.f;
}

// ---------------------------------------------------------------------------
// generic fp32 -> bf16 hi/lo split: W[R][C] -> Whi/Wlo[gridDim.x][Cp]
// ---------------------------------------------------------------------------
__global__ __launch_bounds__(128) void split_w_gen(
    const float* __restrict__ W, ushort* __restrict__ Whi,
    ushort* __restrict__ Wlo, int R, int C, int Cp){
  int j = blockIdx.x;
  for (int k = threadIdx.x; k < Cp; k += 128){
    float x = (j < R && k < C) ? W[(size_t)j*C + k] : 0.f;
    ushort hb = f2bf_rne(x);
    float hf = __uint_as_float(((uint)hb)<<16);
    Whi[(size_t)j*Cp + k] = hb;
    Wlo[(size_t)j*Cp + k] = f2bf_rne(x - hf);
  }
}

// ---------------------------------------------------------------------------
// gi = X @ Wih^T + bih via bf16x3 MFMA. v4: C-writes staged through LDS in
// 4-nt groups so each row's store is one aligned 256B run (16 lanes x float4)
// -> kills the 5.2x write amplification (WRITE_SIZE 920 MB for 179 MB data).
// ---------------------------------------------------------------------------
__global__ __launch_bounds__(256,3) void gi_mfma_v2(
    const int* __restrict__ docs, const float* __restrict__ emb,
    const ushort* __restrict__ Whi, const ushort* __restrict__ Wlo,
    const float* __restrict__ bih, float* __restrict__ gi){
  __shared__ __align__(16) ushort Bhi[2][16*328];
  __shared__ __align__(16) ushort Blo[2][16*328];
  __shared__ __align__(16) float  Cst[64*68];
  __shared__ int toks[64];
  int tid = threadIdx.x;
  int gr0 = blockIdx.x * 64;
  int t  = gr0 >> 10;
  int n0 = gr0 & 1023;
  if (tid < 64) toks[tid] = docs[(n0 + tid)*T_ + t];
  uint4 pb[5];
#pragma unroll
  for (int i=0;i<5;i++){
    int c = tid + i*256;
    int half = (c >= 640) ? 1 : 0; int cc = c - half*640;
    int row = cc/40, o16 = cc - row*40;
    const ushort* src = half ? Wlo : Whi;
    pb[i] = *(const uint4*)&src[(size_t)row*320 + o16*8];
  }
  __syncthreads();   // toks visible
  int w = tid >> 6, L = tid & 63;
  int lrow = L & 15, lseg = L >> 4;
  const float* aptr = emb + (size_t)toks[w*16 + lrow]*300;
  bf16x8 ah[10], al[10];
#pragma unroll
  for (int ks=0; ks<10; ks++){
    int k0 = ks*32 + lseg*8;
    float x[8];
    if (k0 + 8 <= 300){
      float4 v0 = *(const float4*)&aptr[k0];
      float4 v1 = *(const float4*)&aptr[k0+4];
      x[0]=v0.x; x[1]=v0.y; x[2]=v0.z; x[3]=v0.w;
      x[4]=v1.x; x[5]=v1.y; x[6]=v1.z; x[7]=v1.w;
    } else {
#pragma unroll
      for (int u=0;u<8;u++) x[u] = (k0+u < 300) ? aptr[k0+u] : 0.f;
    }
#pragma unroll
    for (int u=0;u<8;u++){
      ushort hb = f2bf_rne(x[u]);
      float lo = x[u] - __uint_as_float(((uint)hb)<<16);
      ah[ks][u] = (short)hb;
      al[ks][u] = (short)f2bf_rne(lo);
    }
  }
#pragma unroll
  for (int i=0;i<5;i++){
    int c = tid + i*256;
    int half = (c >= 640) ? 1 : 0; int cc = c - half*640;
    int row = cc/40, o16 = cc - row*40;
    ushort* dst = half ? Blo[0] : Bhi[0];
    *(uint4*)&dst[row*328 + o16*8] = pb[i];
  }
  __syncthreads();
  int buf = 0;
  int bfb = lrow*328 + lseg*8;
  int rl0 = w*16 + lseg*4;
  f32x4 acc4[4];
  // groups of 4 nt (cols 64g..64g+63), all < 900
  for (int g = 0; g < 14; ++g){
#pragma unroll
    for (int q = 0; q < 4; ++q){
      int nt = g*4 + q;
      // prefetch B(nt+1)  (nt <= 55 here, so nt+1 <= 56 is valid)
#pragma unroll
      for (int i=0;i<5;i++){
        int c = tid + i*256;
        int half = (c >= 640) ? 1 : 0; int cc = c - half*640;
        int row = cc/40, o16 = cc - row*40;
        const ushort* src = half ? Wlo : Whi;
        pb[i] = *(const uint4*)&src[(size_t)((nt+1)*16 + row)*320 + o16*8];
      }
      f32x4 acc = {0.f, 0.f, 0.f, 0.f};
#pragma unroll
      for (int ks=0; ks<10; ks++){
        bf16x8 bh = *(const bf16x8*)&Bhi[buf][bfb + ks*32];
        bf16x8 bl = *(const bf16x8*)&Blo[buf][bfb + ks*32];
        acc = __builtin_amdgcn_mfma_f32_16x16x32_bf16(ah[ks], bh, acc, 0, 0, 0);
        acc = __builtin_amdgcn_mfma_f32_16x16x32_bf16(ah[ks], bl, acc, 0, 0, 0);
        acc = __builtin_amdgcn_mfma_f32_16x16x32_bf16(al[ks], bh, acc, 0, 0, 0);
      }
      acc4[q] = acc;
#pragma unroll
      for (int i=0;i<5;i++){
        int c = tid + i*256;
        int half = (c >= 640) ? 1 : 0; int cc = c - half*640;
        int row = cc/40, o16 = cc - row*40;
        ushort* dst = half ? Blo[buf^1] : Bhi[buf^1];
        *(uint4*)&dst[row*328 + o16*8] = pb[i];
      }
      __syncthreads();
      buf ^= 1;
    }
    // stage 64x64 tile to LDS
#pragma unroll
    for (int q = 0; q < 4; ++q){
#pragma unroll
      for (int r = 0; r < 4; ++r)
        Cst[(rl0 + r)*68 + q*16 + lrow] = acc4[q][r];
    }
    __syncthreads();
    // cooperative aligned 256B-per-row writes (+ bias)
#pragma unroll
    for (int i = 0; i < 4; ++i){
      int idxc = tid + i*256;
      int row = idxc >> 4, c4 = idxc & 15;
      int colb = g*64 + c4*4;
      float4 v = *(float4*)&Cst[row*68 + c4*4];
      float4 bb = *(const float4*)&bih[colb];
      v.x += bb.x; v.y += bb.y; v.z += bb.z; v.w += bb.w;
      *(float4*)&gi[(size_t)(gr0 + row)*GST + colb] = v;
    }
    __syncthreads();
  }
  // tail: nt = 56, cols 896..911, valid 896..899
  {
    f32x4 acc = {0.f, 0.f, 0.f, 0.f};
#pragma unroll
    for (int ks=0; ks<10; ks++){
      bf16x8 bh = *(const bf16x8*)&Bhi[buf][bfb + ks*32];
      bf16x8 bl = *(const bf16x8*)&Blo[buf][bfb + ks*32];
      acc = __builtin_amdgcn_mfma_f32_16x16x32_bf16(ah[ks], bh, acc, 0, 0, 0);
      acc = __builtin_amdgcn_mfma_f32_16x16x32_bf16(ah[ks], bl, acc, 0, 0, 0);
      acc = __builtin_amdgcn_mfma_f32_16x16x32_bf16(al[ks], bh, acc, 0, 0, 0);
    }
    int col = 896 + lrow;
    if (col < 900){
      float bb = bih[col];
#pragma unroll
      for (int r=0;r<4;r++)
        gi[(size_t)(gr0 + rl0 + r)*GST + col] = acc[r] + bb;
    }
  }
}

// ---------------------------------------------------------------------------
// att score via bf16x3 MFMA (writes only score — no layout issue)
// ---------------------------------------------------------------------------
__global__ __launch_bounds__(256,3) void att_mfma_kernel(
    const float* __restrict__ hs, const ushort* __restrict__ Whi,
    const ushort* __restrict__ Wlo, const float* __restrict__ bias,
    const float* __restrict__ ctx, float* __restrict__ score, int Rtot){
  __shared__ __align__(16) ushort Bhi[2][16*328];
  __shared__ __align__(16) ushort Blo[2][16*328];
  int tid = threadIdx.x;
  int r0 = blockIdx.x * 64;
  uint4 pb[5];
#pragma unroll
  for (int i=0;i<5;i++){
    int c = tid + i*256;
    int half = (c >= 640) ? 1 : 0; int cc = c - half*640;
    int row = cc/40, o16 = cc - row*40;
    const ushort* src = half ? Wlo : Whi;
    pb[i] = *(const uint4*)&src[(size_t)row*320 + o16*8];
  }
  int w = tid >> 6, L = tid & 63;
  int lrow = L & 15, lseg = L >> 4;
  int arow = r0 + w*16 + lrow;
  bool avalid = arow < Rtot;
  const float* aptr = hs + (size_t)(avalid ? arow : 0)*300;
  bf16x8 ah[10], al[10];
#pragma unroll
  for (int ks=0; ks<10; ks++){
    int k0 = ks*32 + lseg*8;
    float x[8];
    if (avalid && k0 + 8 <= 300){
      float4 v0 = *(const float4*)&aptr[k0];
      float4 v1 = *(const float4*)&aptr[k0+4];
      x[0]=v0.x; x[1]=v0.y; x[2]=v0.z; x[3]=v0.w;
      x[4]=v1.x; x[5]=v1.y; x[6]=v1.z; x[7]=v1.w;
    } else {
#pragma unroll
      for (int u=0;u<8;u++) x[u] = (avalid && k0+u < 300) ? aptr[k0+u] : 0.f;
    }
#pragma unroll
    for (int u=0;u<8;u++){
      ushort hb = f2bf_rne(x[u]);
      float lo = x[u] - __uint_as_float(((uint)hb)<<16);
      ah[ks][u] = (short)hb;
      al[ks][u] = (short)f2bf_rne(lo);
    }
  }
#pragma unroll
  for (int i=0;i<5;i++){
    int c = tid + i*256;
    int half = (c >= 640) ? 1 : 0; int cc = c - half*640;
    int row = cc/40, o16 = cc - row*40;
    ushort* dst = half ? Blo[0] : Bhi[0];
    *(uint4*)&dst[row*328 + o16*8] = pb[i];
  }
  __syncthreads();
  int buf = 0;
  int bfb = lrow*328 + lseg*8;
  float part[4] = {0.f,0.f,0.f,0.f};
  for (int nt = 0; nt < 19; ++nt){
    if (nt < 18){
#pragma unroll
      for (int i=0;i<5;i++){
        int c = tid + i*256;
        int half = (c >= 640) ? 1 : 0; int cc = c - half*640;
        int row = cc/40, o16 = cc - row*40;
        const ushort* src = half ? Wlo : Whi;
        pb[i] = *(const uint4*)&src[(size_t)((nt+1)*16 + row)*320 + o16*8];
      }
    }
    f32x4 acc = {0.f, 0.f, 0.f, 0.f};
#pragma unroll
    for (int ks=0; ks<10; ks++){
      bf16x8 bh = *(const bf16x8*)&Bhi[buf][bfb + ks*32];
      bf16x8 bl = *(const bf16x8*)&Blo[buf][bfb + ks*32];
      acc = __builtin_amdgcn_mfma_f32_16x16x32_bf16(ah[ks], bh, acc, 0, 0, 0);
      acc = __builtin_amdgcn_mfma_f32_16x16x32_bf16(ah[ks], bl, acc, 0, 0, 0);
      acc = __builtin_amdgcn_mfma_f32_16x16x32_bf16(al[ks], bh, acc, 0, 0, 0);
    }
    int col = nt*16 + lrow;
    if (col < 300){
      float bb = bias[col], cx = ctx[col];
#pragma unroll
      for (int r=0;r<4;r++) part[r] += cx * tanhf(acc[r] + bb);
    }
    if (nt < 18){
#pragma unroll
      for (int i=0;i<5;i++){
        int c = tid + i*256;
        int half = (c >= 640) ? 1 : 0; int cc = c - half*640;
        int row = cc/40, o16 = cc - row*40;
        ushort* dst = half ? Blo[buf^1] : Bhi[buf^1];
        *(uint4*)&dst[row*328 + o16*8] = pb[i];
      }
    }
    __syncthreads();
    buf ^= 1;
  }
#pragma unroll
  for (int off=1; off<16; off<<=1){
#pragma unroll
    for (int r=0;r<4;r++) part[r] += __shfl_xor(part[r], off);
  }
  if (lrow == 0){
    int rbase = r0 + w*16 + lseg*4;
#pragma unroll
    for (int r=0;r<4;r++)
      if (rbase + r < Rtot) score[rbase + r] = part[r];
  }
}

// sentence-level gi (tiny: 64 blocks, fp32), stride GST
__global__ __launch_bounds__(256) void sent_gi_kernel(
    const float* __restrict__ sv, const float* __restrict__ Wih,
    const float* __restrict__ bih, float* __restrict__ gi){
  __shared__ float A[16][G_];
  int r0 = blockIdx.x * 16;
  int s  = r0 >> 6;
  int bb_ = r0 & 63;
  for (int idx = threadIdx.x; idx < 16*75; idx += 256){
    int row = idx / 75, e4 = idx - row*75;
    *(float4*)&A[row][e4*4] =
        *(const float4*)&sv[(((size_t)(bb_+row))*S_ + s)*G_ + e4*4];
  }
  __syncthreads();
  int q = threadIdx.x;
  if (q >= 225) return;
  int j0 = q*4;
  const float4* w0 = (const float4*)(Wih + (size_t)(j0  )*G_);
  const float4* w1 = (const float4*)(Wih + (size_t)(j0+1)*G_);
  const float4* w2 = (const float4*)(Wih + (size_t)(j0+2)*G_);
  const float4* w3 = (const float4*)(Wih + (size_t)(j0+3)*G_);
  float acc[16][4];
#pragma unroll
  for (int i=0;i<16;i++){ acc[i][0]=0.f; acc[i][1]=0.f; acc[i][2]=0.f; acc[i][3]=0.f; }
  for (int e4=0; e4<75; e4++){
    float4 b0=w0[e4], b1=w1[e4], b2=w2[e4], b3=w3[e4];
#pragma unroll
    for (int i=0;i<16;i++){
      float4 av = *(const float4*)&A[i][e4*4];
      acc[i][0] += av.x*b0.x + av.y*b0.y + av.z*b0.z + av.w*b0.w;
      acc[i][1] += av.x*b1.x + av.y*b1.y + av.z*b1.z + av.w*b1.w;
      acc[i][2] += av.x*b2.x + av.y*b2.y + av.z*b2.z + av.w*b2.w;
      acc[i][3] += av.x*b3.x + av.y*b3.y + av.z*b3.z + av.w*b3.w;
    }
  }
  float4 bb = *(const float4*)&bih[j0];
#pragma unroll
  for (int i=0;i<16;i++){
    float4 o4;
    o4.x = acc[i][0]+bb.x; o4.y = acc[i][1]+bb.y;
    o4.z = acc[i][2]+bb.z; o4.w = acc[i][3]+bb.w;
    *(float4*)&gi[((size_t)(s*B_) + bb_ + i)*GST + j0] = o4;
  }
}

// ---------------------------------------------------------------------------
// GRU scan v5 (word): gi stride GST; Wr pinned in VGPRs via keep-alive asm
// (round-11 counters showed VGPR=80 < the 104 floats of Wr -> compiler had
// sunk the W loads back into the step loop, re-streaming W from cache).
// ---------------------------------------------------------------------------
__global__ __launch_bounds__(768,3) void gru_scan_v5(
    const float* __restrict__ gi, const float* __restrict__ W5,
    const float* __restrict__ bhh, float* __restrict__ hs,
    int T, int N){
  int d  = blockIdx.y;
  int n0 = blockIdx.x * 8;
  __shared__ float hl[2][8][160];
  __shared__ float ghp[3][8][452];
  int tid = threadIdx.x;
  for (int idx = tid; idx < 2*8*160; idx += 768) (&hl[0][0][0])[idx] = 0.f;
  bool gact = tid < 675;
  int j2 = gact ? tid % 225 : 0;
  int kh = gact ? tid / 225 : 0;
  float4 Wr[13][2];
  {
    const float4* wb = (const float4*)(W5 + (size_t)(d*3 + kh)*13*225*8);
#pragma unroll
    for (int e4=0;e4<13;e4++){
      Wr[e4][0] = wb[(e4*225 + j2)*2 + 0];
      Wr[e4][1] = wb[(e4*225 + j2)*2 + 1];
    }
  }
  // force register residency: opaque "modification" forbids rematerialization
#pragma unroll
  for (int e4=0;e4<13;e4++){
    asm volatile("" : "+v"(Wr[e4][0].x), "+v"(Wr[e4][0].y),
                      "+v"(Wr[e4][0].z), "+v"(Wr[e4][0].w));
    asm volatile("" : "+v"(Wr[e4][1].x), "+v"(Wr[e4][1].y),
                      "+v"(Wr[e4][1].z), "+v"(Wr[e4][1].w));
  }
  float b0 = 0.f, b1 = 0.f;
  if (gact && kh == 0){
    b0 = bhh[d*450 + 2*j2];
    b1 = bhh[d*450 + 2*j2 + 1];
  }
  int i0 = tid/150,        h0 = tid - i0*150;
  int u1 = tid + 768;
  int i1 = u1/150,         h1 = u1 - i1*150;
  bool e1 = u1 < 1200;
  int buf = 0;
  __syncthreads();
  for (int step = 0; step < T; ++step){
    int t = d ? (T-1-step) : step;
    const float* gib = gi + ((size_t)t*N + n0)*GST + d*450;
    float p0r = gib[(size_t)i0*GST + h0];
    float p0z = gib[(size_t)i0*GST + 150 + h0];
    float p0n = gib[(size_t)i0*GST + 300 + h0];
    float p1r=0.f, p1z=0.f, p1n=0.f;
    if (e1){
      p1r = gib[(size_t)i1*GST + h1];
      p1z = gib[(size_t)i1*GST + 150 + h1];
      p1n = gib[(size_t)i1*GST + 300 + h1];
    }
    if (gact){
      float a0[8], a1[8];
#pragma unroll
      for (int i=0;i<8;i++){ a0[i]=0.f; a1[i]=0.f; }
#pragma unroll
      for (int e4=0;e4<13;e4++){
        float4 w0 = Wr[e4][0], w1 = Wr[e4][1];
#pragma unroll
        for (int i=0;i<8;i++){
          float4 hv = *(const float4*)&hl[buf][i][(kh*13+e4)*4];
          a0[i] += w0.x*hv.x + w0.y*hv.y + w0.z*hv.z + w0.w*hv.w;
          a1[i] += w1.x*hv.x + w1.y*hv.y + w1.z*hv.z + w1.w*hv.w;
        }
      }
#pragma unroll
      for (int i=0;i<8;i++){
        float2 v; v.x = a0[i] + b0; v.y = a1[i] + b1;
        *(float2*)&ghp[kh][i][2*j2] = v;
      }
    }
    __syncthreads();
    {
      float ghr = ghp[0][i0][h0]     + ghp[1][i0][h0]     + ghp[2][i0][h0];
      float ghz = ghp[0][i0][150+h0] + ghp[1][i0][150+h0] + ghp[2][i0][150+h0];
      float ghn = ghp[0][i0][300+h0] + ghp[1][i0][300+h0] + ghp[2][i0][300+h0];
      float hold = hl[buf][i0][h0];
      float r  = sigm(p0r + ghr);
      float z  = sigm(p0z + ghz);
      float nn = tanhf(p0n + r*ghn);
      float h2 = (1.f - z)*nn + z*hold;
      hl[buf^1][i0][h0] = h2;
      hs[((size_t)t*N + n0 + i0)*G_ + d*H_ + h0] = h2;
    }
    if (e1){
      float ghr = ghp[0][i1][h1]     + ghp[1][i1][h1]     + ghp[2][i1][h1];
      float ghz = ghp[0][i1][150+h1] + ghp[1][i1][150+h1] + ghp[2][i1][150+h1];
      float ghn = ghp[0][i1][300+h1] + ghp[1][i1][300+h1] + ghp[2][i1][300+h1];
      float hold = hl[buf][i1][h1];
      float r  = sigm(p1r + ghr);
      float z  = sigm(p1z + ghz);
      float nn = tanhf(p1n + r*ghn);
      float h2 = (1.f - z)*nn + z*hold;
      hl[buf^1][i1][h1] = h2;
      hs[((size_t)t*N + n0 + i1)*G_ + d*H_ + h1] = h2;
    }
    buf ^= 1;
    __syncthreads();
  }
}

// ---------------------------------------------------------------------------
// GRU scan v4 (sentence, tiny): gi stride GST
// ---------------------------------------------------------------------------
template<int R>
__global__ __launch_bounds__(512,2) void gru_scan_v4(
    const float* __restrict__ gi, const float* __restrict__ Wblk,
    const float* __restrict__ bhh, float* __restrict__ hs,
    int T, int N){
  int d  = blockIdx.y;
  int n0 = blockIdx.x * R;
  __shared__ float hl[2][R][152];
  __shared__ float gh[R][452];
  int tid = threadIdx.x;
  for (int idx = tid; idx < 2*R*152; idx += 512) (&hl[0][0][0])[idx] = 0.f;
  bool jact = tid < 450;
  bool hact = tid < 150;
  float4 Wr[38];
  float bj = 0.f;
  {
    const float4* Wb4 = (const float4*)(Wblk + (size_t)d*38*1800);
    int jj = jact ? tid : 0;
#pragma unroll
    for (int e4 = 0; e4 < 38; ++e4) Wr[e4] = Wb4[e4*450 + jj];
    if (jact) bj = bhh[d*450 + tid];
  }
  float hreg[R];
#pragma unroll
  for (int i=0;i<R;i++) hreg[i] = 0.f;
  int buf = 0;
  __syncthreads();
  for (int step = 0; step < T; ++step){
    int t = d ? (T-1-step) : step;
    const float* gib = gi + ((size_t)t*N + n0)*GST + d*450;
    float pre[R][3];
    if (hact){
#pragma unroll
      for (int i=0;i<R;i++){
        pre[i][0] = gib[(size_t)i*GST + tid];
        pre[i][1] = gib[(size_t)i*GST + 150 + tid];
        pre[i][2] = gib[(size_t)i*GST + 300 + tid];
      }
    }
    if (jact){
      float acc[R];
#pragma unroll
      for (int i=0;i<R;i++) acc[i] = 0.f;
#pragma unroll
      for (int e4 = 0; e4 < 38; ++e4){
        float4 w = Wr[e4];
#pragma unroll
        for (int i=0;i<R;i++){
          float4 hv = *(const float4*)&hl[buf][i][e4*4];
          acc[i] += w.x*hv.x + w.y*hv.y + w.z*hv.z + w.w*hv.w;
        }
      }
#pragma unroll
      for (int i=0;i<R;i++) gh[i][tid] = acc[i] + bj;
    }
    __syncthreads();
    if (hact){
#pragma unroll
      for (int i=0;i<R;i++){
        float r  = sigm(pre[i][0] + gh[i][tid]);
        float z  = sigm(pre[i][1] + gh[i][150+tid]);
        float nn = tanhf(pre[i][2] + r*gh[i][300+tid]);
        float h2 = (1.f - z)*nn + z*hreg[i];
        hreg[i] = h2;
        hl[buf^1][i][tid] = h2;
        hs[((size_t)t*N + n0 + i)*G_ + d*H_ + tid] = h2;
      }
    }
    buf ^= 1;
    __syncthreads();
  }
}

// softmax over t (per n) + weighted sum
__global__ __launch_bounds__(256) void att_combine_kernel(
    const float* __restrict__ score, const float* __restrict__ hs,
    float* __restrict__ out, int T, int N){
  int n = blockIdx.x;
  __shared__ float wa[64];
  if (threadIdx.x < T) wa[threadIdx.x] = score[threadIdx.x*N + n];
  __syncthreads();
  float m = -1e30f;
  for (int t=0;t<T;t++) m = fmaxf(m, wa[t]);
  float den = 0.f;
  for (int t=0;t<T;t++) den += __expf(wa[t]-m);
  float inv = 1.f/den;
  __syncthreads();
  if (threadIdx.x < T) wa[threadIdx.x] = __expf(wa[threadIdx.x]-m)*inv;
  __syncthreads();
  for (int g = threadIdx.x; g < G_; g += 256){
    float acc = 0.f;
    for (int t=0;t<T;t++) acc += wa[t] * hs[((size_t)t*N+n)*G_ + g];
    out[(size_t)n*G_ + g] = acc;
  }
}

// one wave per (b,k): both cosine sims
__global__ __launch_bounds__(256) void cossim_kernel(
    const int* __restrict__ cand, const int* __restrict__ sens,
    const float* __restrict__ ent, const float* __restrict__ sv,
    const float* __restrict__ odoc, float* __restrict__ sim){
  int w = (blockIdx.x*256 + threadIdx.x) >> 6;
  int lane = threadIdx.x & 63;
  if (w >= B_*NC_) return;
  int b = w / NC_, k = w - b*NC_;
  const float* c  = ent + (size_t)cand[b*NC_ + k]*E_;
  const float* a1 = sv  + ((size_t)b*S_ + sens[b])*G_;
  const float* a2 = odoc + (size_t)b*G_;
  float d1=0.f,d2=0.f,cc=0.f,n1=0.f,n2=0.f;
  for (int e = lane; e < E_; e += 64){
    float cv=c[e], v1=a1[e], v2=a2[e];
    d1+=v1*cv; d2+=v2*cv; cc+=cv*cv; n1+=v1*v1; n2+=v2*v2;
  }
  for (int off=32; off; off>>=1){
    d1+=__shfl_xor(d1,off); d2+=__shfl_xor(d2,off); cc+=__shfl_xor(cc,off);
    n1+=__shfl_xor(n1,off); n2+=__shfl_xor(n2,off);
  }
  if (lane == 0){
    float nc = sqrtf(cc);
    sim[(size_t)b*600 + k]       = d1 / fmaxf(sqrtf(n1)*nc, 1e-8f);
    sim[(size_t)b*600 + 300 + k] = d2 / fmaxf(sqrtf(n2)*nc, 1e-8f);
  }
}

// score = sim @ linW^T + linb; gold gather; argmax (first-max tie rule)
__global__ __launch_bounds__(256) void final_kernel(
    const float* __restrict__ sim, const float* __restrict__ linW,
    const float* __restrict__ linb, const int* __restrict__ idx,
    float* __restrict__ out){
  int b = blockIdx.x;
  __shared__ float ss[600];
  __shared__ float sc[300];
  __shared__ float bv[256];
  __shared__ int   bi[256];
  for (int j = threadIdx.x; j < 600; j += 256) ss[j] = sim[(size_t)b*600 + j];
  __syncthreads();
  float bestv = -1e30f; int besti = 0;
  for (int i = threadIdx.x; i < 300; i += 256){
    const float4* wr = (const float4*)(linW + (size_t)i*600);
    float acc = linb[i];
    for (int j4=0; j4<150; j4++){
      float4 w = wr[j4];
      int j = j4*4;
      acc += w.x*ss[j] + w.y*ss[j+1] + w.z*ss[j+2] + w.w*ss[j+3];
    }
    sc[i] = acc;
    out[64 + (size_t)b*300 + i] = acc;
    if (acc > bestv){ bestv = acc; besti = i; }
  }
  bv[threadIdx.x] = bestv; bi[threadIdx.x] = besti;
  __syncthreads();
  for (int s=128; s; s>>=1){
    if (threadIdx.x < s){
      float ov = bv[threadIdx.x+s]; int oi = bi[threadIdx.x+s];
      if (ov > bv[threadIdx.x] || (ov == bv[threadIdx.x] && oi < bi[threadIdx.x])){
        bv[threadIdx.x] = ov; bi[threadIdx.x] = oi;
      }
    }
    __syncthreads();
  }
  if (threadIdx.x == 0){
    out[b] = sc[idx[b]-1];
    out[64 + 64*300 + b] = (float)bi[0];
  }
}

extern "C" void kernel_launch(void* const* d_in, const int* in_sizes, int n_in,
                              void* d_out, int out_size, void* d_ws, size_t ws_size,
                              hipStream_t stream){
  const int*   docs  = (const int*)d_in[0];
  const int*   sens  = (const int*)d_in[1];
  const int*   cand  = (const int*)d_in[2];
  const int*   idx   = (const int*)d_in[3];
  const float* wemb  = (const float*)d_in[4];
  const float* eemb  = (const float*)d_in[5];
  const float* Wih_w = (const float*)d_in[6];
  const float* Whh_w = (const float*)d_in[7];
  const float* bih_w = (const float*)d_in[8];
  const float* bhh_w = (const float*)d_in[9];
  const float* attW_w= (const float*)d_in[10];
  const float* attb_w= (const float*)d_in[11];
  const float* ctx_w = (const float*)d_in[12];
  const float* Wih_s = (const float*)d_in[13];
  const float* Whh_s = (const float*)d_in[14];
  const float* bih_s = (const float*)d_in[15];
  const float* bhh_s = (const float*)d_in[16];
  const float* attW_s= (const float*)d_in[17];
  const float* attb_s= (const float*)d_in[18];
  const float* ctx_s = (const float*)d_in[19];
  const float* linW  = (const float*)d_in[20];
  const float* linb  = (const float*)d_in[21];

  float* ws = (float*)d_ws;
  size_t off = 0;
  float* gi_w    = ws + off; off += (size_t)T_*NW_*GST;   // 188.7 MB (padded)
  float* hs_w    = ws + off; off += (size_t)T_*NW_*G_;    // 59 MB
  float* score_w = ws + off; off += (size_t)T_*NW_;
  float* sv      = ws + off; off += (size_t)NW_*G_;
  float* hs_s    = ws + off; off += (size_t)S_*B_*G_;
  float* score_s = ws + off; off += (size_t)S_*B_;
  float* odoc    = ws + off; off += (size_t)B_*G_;
  float* sim     = ws + off; off += (size_t)B_*600;
  float* Wblk_s  = ws + off; off += (size_t)2*38*450*4;   // sentence Whh tiles
  float* W5_w    = ws + off; off += (size_t)2*3*13*225*8; // word Whh v5 tiles
  ushort* Whi    = (ushort*)(ws + off); off += (size_t)912*320/2;
  ushort* Wlo    = (ushort*)(ws + off); off += (size_t)912*320/2;
  ushort* WAhi   = (ushort*)(ws + off); off += (size_t)304*320/2;
  ushort* WAlo   = (ushort*)(ws + off); off += (size_t)304*320/2;
  ushort* WShi   = (ushort*)(ws + off); off += (size_t)304*320/2;
  ushort* WSlo   = (ushort*)(ws + off); off += (size_t)304*320/2;
  float* gi_s    = gi_w;   // aliases gi_w: word gi is dead before sent_gi runs

  float* out = (float*)d_out;

  // one-time weight preps
  prep_whh_kernel<<<(2*38*450*4+255)/256, 256, 0, stream>>>(Whh_s, Wblk_s);
  prep_whh_v5<<<(2*3*13*225*8+255)/256, 256, 0, stream>>>(Whh_w, W5_w);
  split_w_gen<<<912, 128, 0, stream>>>(Wih_w, Whi, Wlo, 900, 300, 320);
  split_w_gen<<<304, 128, 0, stream>>>(attW_w, WAhi, WAlo, 300, 300, 320);
  split_w_gen<<<304, 128, 0, stream>>>(attW_s, WShi, WSlo, 300, 300, 320);

  // word level
  gi_mfma_v2<<<RW_/64, 256, 0, stream>>>(docs, wemb, Whi, Wlo, bih_w, gi_w);
  gru_scan_v5<<<dim3(NW_/8, 2), 768, 0, stream>>>(gi_w, W5_w, bhh_w,
                                                  hs_w, T_, NW_);
  att_mfma_kernel<<<RW_/64, 256, 0, stream>>>(hs_w, WAhi, WAlo, attb_w,
                                              ctx_w, score_w, RW_);
  att_combine_kernel<<<NW_, 256, 0, stream>>>(score_w, hs_w, sv, T_, NW_);

  // sentence level
  sent_gi_kernel<<<RS_/16, 256, 0, stream>>>(sv, Wih_s, bih_s, gi_s);
  gru_scan_v4<2><<<dim3(B_/2, 2), 512, 0, stream>>>(gi_s, Wblk_s, bhh_s,
                                                    hs_s, S_, B_);
  att_mfma_kernel<<<RS_/64, 256, 0, stream>>>(hs_s, WShi, WSlo, attb_s,
                                              ctx_s, score_s, RS_);
  att_combine_kernel<<<B_, 256, 0, stream>>>(score_s, hs_s, odoc, S_, B_);

  // similarity + linear + gold + argmax
  cossim_kernel<<<(B_*NC_*64)/256, 256, 0, stream>>>(cand, sens, eemb, sv, odoc, sim);
  final_kernel<<<B_, 256, 0, stream>>>(sim, linW, linb, idx, out);
}